// Round 2
// baseline (7468.762 us; speedup 1.0000x reference)
//
#include <hip/hip_runtime.h>

#define CDIV(a,b) (((a)+(b)-1)/(b))
#define EE 40000
#define TOTROWS 170000

struct __align__(8) us4 { unsigned short x, y, z, w; };

__device__ __forceinline__ float eluf(float x) { return x > 0.f ? x : expm1f(x); }
__device__ __forceinline__ float sigf(float x) { return 1.f / (1.f + expf(-x)); }
__device__ __forceinline__ float b2f(unsigned short u) { return __uint_as_float(((unsigned)u) << 16); }
__device__ __forceinline__ unsigned short f2b(float f) {
  unsigned x = __float_as_uint(f);
  x += 0x7FFFu + ((x >> 16) & 1u);
  return (unsigned short)(x >> 16);
}
__device__ __forceinline__ float2 b2f2(unsigned u) {  // [lo half, hi half] -> 2 floats
  return make_float2(__uint_as_float(u << 16), __uint_as_float(u & 0xFFFF0000u));
}

__device__ __forceinline__ void atomicMaxFloat(float* addr, float val) {
  if (val >= 0.f) atomicMax((int*)addr, __float_as_int(val));
  else            atomicMin((unsigned int*)addr, __float_as_uint(val));
}

// ---------------- scalar prep
__global__ void prep_scalars(const float* __restrict__ theta, const float* __restrict__ rel_imp,
                             float* __restrict__ scal) {
  int t = threadIdx.x;
  if (t < 7) scal[t] = 1.f - sigf(theta[t]);
  if (t < 21) {
    const int partner[7] = {1, 0, 4, 5, 2, 3, -1};
    int l = t / 7, r = t % 7;
    float rw = sigf(rel_imp[t]);
    float w;
    if (partner[r] < 0) w = 1.f;
    else {
      float rwp = sigf(rel_imp[l * 7 + partner[r]]);
      float e0 = expf(rw), e1 = expf(rwp);
      w = e0 / (e0 + e1);
    }
    scal[8 + t] = w * rw;
  }
}

// ---------------- input projection: h = elu(x @ Win + b_in)  (bf16 out)
__global__ __launch_bounds__(128) void in_proj(const float* __restrict__ x, const float* __restrict__ Win,
                                               const float* __restrict__ bin, unsigned short* __restrict__ Hout,
                                               int n, int F) {
  __shared__ float xs[32];
  int nd = blockIdx.x;
  if (nd >= n) return;
  if (threadIdx.x < F) xs[threadIdx.x] = x[nd * F + threadIdx.x];
  __syncthreads();
  int c = threadIdx.x;
  float acc = bin[c];
  for (int f = 0; f < F; f++) acc = fmaf(xs[f], Win[f * 128 + c], acc);
  Hout[(size_t)nd * 128 + c] = f2b(eluf(acc));
}

// ---------------- GEMM: C[n,128] = A[n,K] @ W[K,128]
// MODE 0: A bf16, C bf16 = acc                      (Q/K/V projections)
// MODE 1: A f32,  C bf16 += coef*(acc + deg*bvec)   (accumulate messages into comb)
// MODE 4: A f32,  C bf16  = coef*(acc + deg*bvec)   (init comb)
// MODE 2: A bf16, C f32  = b2f(hres) + acc + bvec   (residual + Wo + bo -> pre-LN y)
// MODE 3: A bf16 (K=256), C f32 = elu(acc + bvec)   (edge-head hidden)
template<int MODE>
__global__ __launch_bounds__(256) void gemm_nk(const void* __restrict__ Ap, const float* __restrict__ W,
                                               void* __restrict__ Cp, int n,
                                               const float* __restrict__ coefp,
                                               const float* __restrict__ deg,
                                               const float* __restrict__ bvec,
                                               const unsigned short* __restrict__ hres) {
  constexpr int KK = (MODE == 3) ? 256 : 128;
  constexpr bool ABF = (MODE != 1 && MODE != 4);
  __shared__ __align__(16) float Wl[64 * 128];
  __shared__ __align__(16) float At[64 * 68];
  const unsigned short* Ab = (const unsigned short*)Ap;
  const float* Af = (const float*)Ap;
  int tid = threadIdx.x;
  int base = blockIdx.x * 64;
  int cg = tid & 31, rg = tid >> 5;
  float acc[8][4];
#pragma unroll
  for (int i = 0; i < 8; i++)
#pragma unroll
    for (int j = 0; j < 4; j++) acc[i][j] = 0.f;

  constexpr int nphase = KK >> 6;
  for (int p = 0; p < nphase; p++) {
#pragma unroll
    for (int i = 0; i < 32; i++) {
      int idx = tid + i * 256;                 // 0..8191
      Wl[idx] = W[(p << 6) * 128 + idx];
    }
#pragma unroll
    for (int i = 0; i < 16; i++) {
      int idx = tid + i * 256;                 // 0..4095
      int r = idx >> 6, kk = idx & 63;
      int row = base + r;
      float v = 0.f;
      if (row < n) {
        size_t ai = (size_t)row * KK + (p << 6) + kk;
        v = ABF ? b2f(Ab[ai]) : Af[ai];
      }
      At[kk * 68 + r] = v;
    }
    __syncthreads();
#pragma unroll 2
    for (int kk = 0; kk < 64; kk++) {
      float4 a0 = *(const float4*)&At[kk * 68 + rg * 8];
      float4 a1 = *(const float4*)&At[kk * 68 + rg * 8 + 4];
      float4 w4 = *(const float4*)&Wl[kk * 128 + cg * 4];
      float av[8] = {a0.x, a0.y, a0.z, a0.w, a1.x, a1.y, a1.z, a1.w};
      float wv[4] = {w4.x, w4.y, w4.z, w4.w};
#pragma unroll
      for (int i = 0; i < 8; i++)
#pragma unroll
        for (int j = 0; j < 4; j++) acc[i][j] = fmaf(av[i], wv[j], acc[i][j]);
    }
    __syncthreads();
  }

  float coef = (MODE == 1 || MODE == 4) ? *coefp : 0.f;
#pragma unroll
  for (int i = 0; i < 8; i++) {
    int row = base + rg * 8 + i;
    if (row >= n) continue;
    float a0 = acc[i][0], a1 = acc[i][1], a2 = acc[i][2], a3 = acc[i][3];
    if (MODE == 0) {
      unsigned short* cp = (unsigned short*)Cp + (size_t)row * 128 + cg * 4;
      us4 o; o.x = f2b(a0); o.y = f2b(a1); o.z = f2b(a2); o.w = f2b(a3);
      *(us4*)cp = o;
    } else if (MODE == 1 || MODE == 4) {
      unsigned short* cp = (unsigned short*)Cp + (size_t)row * 128 + cg * 4;
      float dg = deg[row];
      float m0 = coef * (a0 + dg * bvec[cg * 4 + 0]);
      float m1 = coef * (a1 + dg * bvec[cg * 4 + 1]);
      float m2 = coef * (a2 + dg * bvec[cg * 4 + 2]);
      float m3 = coef * (a3 + dg * bvec[cg * 4 + 3]);
      if (MODE == 1) {
        us4 ov = *(us4*)cp;
        m0 += b2f(ov.x); m1 += b2f(ov.y); m2 += b2f(ov.z); m3 += b2f(ov.w);
      }
      us4 o; o.x = f2b(m0); o.y = f2b(m1); o.z = f2b(m2); o.w = f2b(m3);
      *(us4*)cp = o;
    } else if (MODE == 2) {
      float* cp = (float*)Cp + (size_t)row * 128 + cg * 4;
      us4 hv = *(const us4*)&hres[(size_t)row * 128 + cg * 4];
      float4 o;
      o.x = b2f(hv.x) + a0 + bvec[cg * 4 + 0];
      o.y = b2f(hv.y) + a1 + bvec[cg * 4 + 1];
      o.z = b2f(hv.z) + a2 + bvec[cg * 4 + 2];
      o.w = b2f(hv.w) + a3 + bvec[cg * 4 + 3];
      *(float4*)cp = o;
    } else {  // MODE 3
      float* cp = (float*)Cp + (size_t)row * 128 + cg * 4;
      float4 o;
      o.x = eluf(a0 + bvec[cg * 4 + 0]);
      o.y = eluf(a1 + bvec[cg * 4 + 1]);
      o.z = eluf(a2 + bvec[cg * 4 + 2]);
      o.w = eluf(a3 + bvec[cg * 4 + 3]);
      *(float4*)cp = o;
    }
  }
}

// ---------------- per-relation clears (S f32, m, z, deg)
__global__ void clear_rel(float* __restrict__ S, float* __restrict__ m, float* __restrict__ z,
                          float* __restrict__ deg, int nd) {
  int idx = blockIdx.x * 256 + threadIdx.x;
  if (idx < nd * 128) S[idx] = 0.f;
  if (idx < nd * 4) { m[idx] = -3.0e38f; z[idx] = 0.f; }
  if (idx < nd) deg[idx] = 0.f;
}

// ---------------- attention scores + segment max (Q,K bf16)
__global__ void score_max(const unsigned short* __restrict__ Q, const unsigned short* __restrict__ Kb,
                          const int* __restrict__ src, const int* __restrict__ dst,
                          const float* __restrict__ ew, const float* __restrict__ ews,
                          float* __restrict__ sbuf, float* __restrict__ m) {
  int idx = blockIdx.x * 256 + threadIdx.x;
  if (idx >= EE * 4) return;
  int e = idx >> 2, hd = idx & 3;
  int s = src[e], d = dst[e];
  const uint4* qp = (const uint4*)&Q[(size_t)d * 128 + hd * 32];
  const uint4* kp = (const uint4*)&Kb[(size_t)s * 128 + hd * 32];
  float acc = 0.f;
#pragma unroll
  for (int i = 0; i < 4; i++) {
    uint4 qu = qp[i], ku = kp[i];
    float2 q0 = b2f2(qu.x), k0 = b2f2(ku.x);
    float2 q1 = b2f2(qu.y), k1 = b2f2(ku.y);
    float2 q2 = b2f2(qu.z), k2 = b2f2(ku.z);
    float2 q3 = b2f2(qu.w), k3 = b2f2(ku.w);
    acc += q0.x * k0.x + q0.y * k0.y + q1.x * k1.x + q1.y * k1.y
         + q2.x * k2.x + q2.y * k2.y + q3.x * k3.x + q3.y * k3.y;
  }
  float sc = acc * 0.17677669529663687f * ew[e] * (*ews);
  sbuf[idx] = sc;
  atomicMaxFloat(&m[d * 4 + hd], sc);
}

// ---------------- exp(s-m), segment sum, degree count
__global__ void exp_sum(const int* __restrict__ dst, const float* __restrict__ m,
                        float* __restrict__ sbuf, float* __restrict__ z, float* __restrict__ deg) {
  int idx = blockIdx.x * 256 + threadIdx.x;
  if (idx >= EE * 4) return;
  int e = idx >> 2, hd = idx & 3;
  int d = dst[e];
  float ex = expf(sbuf[idx] - m[d * 4 + hd]);
  sbuf[idx] = ex;
  atomicAdd(&z[d * 4 + hd], ex);
  if (hd == 0) atomicAdd(&deg[d], 1.f);
}

// ---------------- scatter p-weighted V (bf16) into S (f32 atomics)
__global__ void scatter_wv(const int* __restrict__ src, const int* __restrict__ dst,
                           const unsigned short* __restrict__ V, const float* __restrict__ sbuf,
                           const float* __restrict__ z, float* __restrict__ S) {
  int idx = blockIdx.x * 256 + threadIdx.x;
  if (idx >= EE * 16) return;
  int e = idx >> 4, c8 = idx & 15;
  int c = c8 * 8, hd = c >> 5;
  int s = src[e], d = dst[e];
  float p = sbuf[e * 4 + hd] / (z[d * 4 + hd] + 1e-10f);
  const uint4 v = *(const uint4*)&V[(size_t)s * 128 + c];
  float2 f0 = b2f2(v.x), f1 = b2f2(v.y), f2 = b2f2(v.z), f3 = b2f2(v.w);
  float* Sp = &S[(size_t)d * 128 + c];
  atomicAdd(Sp + 0, f0.x * p); atomicAdd(Sp + 1, f0.y * p);
  atomicAdd(Sp + 2, f1.x * p); atomicAdd(Sp + 3, f1.y * p);
  atomicAdd(Sp + 4, f2.x * p); atomicAdd(Sp + 5, f2.y * p);
  atomicAdd(Sp + 6, f3.x * p); atomicAdd(Sp + 7, f3.y * p);
}

// ---------------- layernorm + elu  (y f32 in, h bf16 out; one wave per node)
__global__ __launch_bounds__(256) void ln_elu(const float* __restrict__ Y, const float* __restrict__ g,
                                              const float* __restrict__ b, unsigned short* __restrict__ Hout,
                                              int n) {
  int lane = threadIdx.x & 63;
  int node = blockIdx.x * 4 + (threadIdx.x >> 6);
  if (node >= n) return;
  float y0 = Y[(size_t)node * 128 + lane], y1 = Y[(size_t)node * 128 + 64 + lane];
  float sum = y0 + y1;
#pragma unroll
  for (int mm = 32; mm; mm >>= 1) sum += __shfl_xor(sum, mm);
  float mu = sum * (1.f / 128.f);
  float d0 = y0 - mu, d1 = y1 - mu;
  float vs = d0 * d0 + d1 * d1;
#pragma unroll
  for (int mm = 32; mm; mm >>= 1) vs += __shfl_xor(vs, mm);
  float rs = rsqrtf(vs * (1.f / 128.f) + 1e-5f);
  float o0 = d0 * rs * g[lane] + b[lane];
  float o1 = d1 * rs * g[64 + lane] + b[64 + lane];
  Hout[(size_t)node * 128 + lane] = f2b(eluf(o0));
  Hout[(size_t)node * 128 + 64 + lane] = f2b(eluf(o1));
}

__global__ void elu_bf16(unsigned short* __restrict__ x, int nelem) {
  int idx = blockIdx.x * 256 + threadIdx.x;
  if (idx >= nelem) return;
  x[idx] = f2b(eluf(b2f(x[idx])));
}

// ---------------- risk head (h bf16)
__global__ __launch_bounds__(256) void risk_head(const unsigned short* __restrict__ Hh,
                                                 const float* __restrict__ Wr1, const float* __restrict__ br1,
                                                 const float* __restrict__ Wr2, const float* __restrict__ br2,
                                                 float* __restrict__ out, int n) {
  int lane = threadIdx.x & 63;
  int node = blockIdx.x * 4 + (threadIdx.x >> 6);
  if (node >= n) return;
  const unsigned short* hp = &Hh[(size_t)node * 128];
  float acc = br1[lane];
  for (int k = 0; k < 128; k++) acc = fmaf(b2f(hp[k]), Wr1[k * 64 + lane], acc);
  float hid = eluf(acc);
  float v = hid * Wr2[lane];
#pragma unroll
  for (int mm = 32; mm; mm >>= 1) v += __shfl_xor(v, mm);
  if (lane == 0) out[node] = sigf(v + br2[0]);
}

// ---------------- edge head: gather concat rows (bf16)
__global__ void edge_cat(const unsigned short* __restrict__ hs, const unsigned short* __restrict__ hd_,
                         const int* __restrict__ src, const int* __restrict__ dst,
                         unsigned short* __restrict__ catb) {
  int idx = blockIdx.x * 256 + threadIdx.x;
  if (idx >= EE * 32) return;
  int e = idx >> 5, part = idx & 31;
  uint4 v = (part < 16) ? *(const uint4*)&hs[(size_t)src[e] * 128 + part * 8]
                        : *(const uint4*)&hd_[(size_t)dst[e] * 128 + (part - 16) * 8];
  *(uint4*)&catb[(size_t)e * 256 + part * 8] = v;
}

// ---------------- edge head final reduce (hidden f32)
__global__ __launch_bounds__(256) void edge_out(const float* __restrict__ hid, const float* __restrict__ We2,
                                                const float* __restrict__ be2, float* __restrict__ out) {
  int lane = threadIdx.x & 63;
  int e = blockIdx.x * 4 + (threadIdx.x >> 6);
  if (e >= EE) return;
  float v = hid[(size_t)e * 128 + lane] * We2[lane] + hid[(size_t)e * 128 + 64 + lane] * We2[64 + lane];
#pragma unroll
  for (int mm = 32; mm; mm >>= 1) v += __shfl_xor(v, mm);
  if (lane == 0) out[e] = sigf(v + be2[0]);
}

extern "C" void kernel_launch(void* const* d_in, const int* in_sizes, int n_in,
                              void* d_out, int out_size, void* d_ws, size_t ws_size,
                              hipStream_t stream) {
  (void)in_sizes; (void)n_in; (void)out_size;
  static const int NCNT_[5] = {60000, 20000, 40000, 40000, 10000};
  static const int FEAT_[5] = {22, 6, 14, 5, 9};
  static const int RSI[7] = {0, 1, 0, 0, 2, 4, 0};
  static const int RDI[7] = {1, 1, 2, 3, 2, 3, 0};
  static const int RFIRST[7] = {1, 0, 1, 1, 0, 0, 1};   // 1 = first relation for its dst type (MODE 4)
  static const int ROFF[5] = {0, 60000, 80000, 120000, 160000};

  const float* x[5];    for (int i = 0; i < 5; i++) x[i] = (const float*)d_in[i];
  const int*   ei     = (const int*)d_in[5];
  const float* ew     = (const float*)d_in[6];
  const float* theta  = (const float*)d_in[7];
  const float* Win[5]; for (int i = 0; i < 5; i++) Win[i] = (const float*)d_in[8 + i];
  const float* b_in   = (const float*)d_in[13];
  const float* Wq     = (const float*)d_in[14];
  const float* Wk     = (const float*)d_in[15];
  const float* Wv     = (const float*)d_in[16];
  const float* Wmsg   = (const float*)d_in[17];
  const float* bmsg   = (const float*)d_in[18];
  const float* relimp = (const float*)d_in[19];
  const float* Wo     = (const float*)d_in[20];
  const float* bo     = (const float*)d_in[21];
  const float* lng    = (const float*)d_in[22];
  const float* lnb    = (const float*)d_in[23];
  const float* Wr1    = (const float*)d_in[24];
  const float* br1    = (const float*)d_in[25];
  const float* Wr2    = (const float*)d_in[26];
  const float* br2    = (const float*)d_in[27];
  const float* We1    = (const float*)d_in[28];
  const float* be1    = (const float*)d_in[29];
  const float* We2    = (const float*)d_in[30];
  const float* be2    = (const float*)d_in[31];
  float* out = (float*)d_out;

  // ---- workspace layout (~167 MB) ----
  char* ws = (char*)d_ws;
  size_t off = 0;
  auto alloc = [&](size_t bytes) -> void* {
    void* p = (void*)(ws + off);
    off = (off + bytes + 255) & ~(size_t)255;
    return p;
  };
  unsigned short* h    = (unsigned short*)alloc((size_t)TOTROWS * 128 * 2);
  unsigned short* comb = (unsigned short*)alloc((size_t)TOTROWS * 128 * 2);  // reused as catb for edge heads
  unsigned short* Qb   = (unsigned short*)alloc((size_t)60000 * 128 * 2);
  unsigned short* Kb   = (unsigned short*)alloc((size_t)60000 * 128 * 2);
  unsigned short* Vb   = (unsigned short*)alloc((size_t)60000 * 128 * 2);
  float* Sb   = (float*)alloc((size_t)60000 * 128 * 4);   // scatter target / pre-LN y / edge hidden
  float* sbuf = (float*)alloc((size_t)EE * 4 * 4);
  float* mb   = (float*)alloc((size_t)60000 * 4 * 4);
  float* zb   = (float*)alloc((size_t)60000 * 4 * 4);
  float* degb = (float*)alloc((size_t)60000 * 4);
  float* scal = (float*)alloc(256);
  if (off > ws_size) return;   // diagnostic fallback: clean absmax failure instead of a fault

  prep_scalars<<<1, 64, 0, stream>>>(theta, relimp, scal);

  for (int t = 0; t < 5; t++)
    in_proj<<<NCNT_[t], 128, 0, stream>>>(x[t], Win[t], b_in + t * 128,
                                          h + (size_t)ROFF[t] * 128, NCNT_[t], FEAT_[t]);

  for (int l = 0; l < 3; l++) {
    for (int r = 0; r < 7; r++) {
      int si = RSI[r], di = RDI[r];
      int nds = NCNT_[si], ndd = NCNT_[di];
      const unsigned short* hs = h + (size_t)ROFF[si] * 128;
      const unsigned short* hd = h + (size_t)ROFF[di] * 128;
      const int* src = ei + (size_t)r * 2 * EE;
      const int* dst = src + EE;
      size_t wofs = (size_t)(l * 7 + r) * 128 * 128;
      gemm_nk<0><<<CDIV(ndd, 64), 256, 0, stream>>>(hd, Wq + wofs, Qb, ndd, nullptr, nullptr, nullptr, nullptr);
      gemm_nk<0><<<CDIV(nds, 64), 256, 0, stream>>>(hs, Wk + wofs, Kb, nds, nullptr, nullptr, nullptr, nullptr);
      gemm_nk<0><<<CDIV(nds, 64), 256, 0, stream>>>(hs, Wv + wofs, Vb, nds, nullptr, nullptr, nullptr, nullptr);
      clear_rel<<<CDIV(ndd * 128, 256), 256, 0, stream>>>(Sb, mb, zb, degb, ndd);
      score_max<<<CDIV(EE * 4, 256), 256, 0, stream>>>(Qb, Kb, src, dst, ew + (size_t)r * EE, scal + r, sbuf, mb);
      exp_sum<<<CDIV(EE * 4, 256), 256, 0, stream>>>(dst, mb, sbuf, zb, degb);
      scatter_wv<<<CDIV(EE * 16, 256), 256, 0, stream>>>(src, dst, Vb, sbuf, zb, Sb);
      unsigned short* cdst = comb + (size_t)ROFF[di] * 128;
      if (RFIRST[r])
        gemm_nk<4><<<CDIV(ndd, 64), 256, 0, stream>>>(Sb, Wmsg + wofs, cdst, ndd,
                                                      scal + 8 + l * 7 + r, degb, bmsg + (l * 7 + r) * 128, nullptr);
      else
        gemm_nk<1><<<CDIV(ndd, 64), 256, 0, stream>>>(Sb, Wmsg + wofs, cdst, ndd,
                                                      scal + 8 + l * 7 + r, degb, bmsg + (l * 7 + r) * 128, nullptr);
    }
    for (int i = 0; i < 4; i++) {
      unsigned short* hi = h + (size_t)ROFF[i] * 128;
      unsigned short* ci = comb + (size_t)ROFF[i] * 128;
      gemm_nk<2><<<CDIV(NCNT_[i], 64), 256, 0, stream>>>(ci, Wo + (size_t)(l * 5 + i) * 128 * 128, Sb, NCNT_[i],
                                                         nullptr, nullptr, bo + (l * 5 + i) * 128, hi);
      ln_elu<<<CDIV(NCNT_[i], 4), 256, 0, stream>>>(Sb, lng + (l * 5 + i) * 128, lnb + (l * 5 + i) * 128,
                                                    hi, NCNT_[i]);
    }
    elu_bf16<<<CDIV(10000 * 128, 256), 256, 0, stream>>>(h + (size_t)ROFF[4] * 128, 10000 * 128);
  }

  // risk heads (nodes already in output order)
  risk_head<<<CDIV(TOTROWS, 4), 256, 0, stream>>>(h, Wr1, br1, Wr2, br2, out, TOTROWS);

  // edge heads (comb reused as concat buffer)
  for (int r = 0; r < 7; r++) {
    int si = RSI[r], di = RDI[r];
    const int* src = ei + (size_t)r * 2 * EE;
    const int* dst = src + EE;
    edge_cat<<<CDIV(EE * 32, 256), 256, 0, stream>>>(h + (size_t)ROFF[si] * 128, h + (size_t)ROFF[di] * 128,
                                                     src, dst, comb);
    gemm_nk<3><<<CDIV(EE, 64), 256, 0, stream>>>(comb, We1, Sb, EE, nullptr, nullptr, be1, nullptr);
    edge_out<<<CDIV(EE, 4), 256, 0, stream>>>(Sb, We2, be2, out + TOTROWS + (size_t)r * EE);
  }
}

// Round 3
// 5178.592 us; speedup vs baseline: 1.4422x; 1.4422x over previous
//
#include <hip/hip_runtime.h>

#define CDIV(a,b) (((a)+(b)-1)/(b))
#define EE 40000
#define TOTROWS 170000

typedef unsigned short ushort_t;
typedef short bf16x8 __attribute__((ext_vector_type(8)));
typedef float f32x4 __attribute__((ext_vector_type(4)));

__device__ __forceinline__ float eluf(float x) { return x > 0.f ? x : expm1f(x); }
__device__ __forceinline__ float sigf(float x) { return 1.f / (1.f + expf(-x)); }
__device__ __forceinline__ float b2f(ushort_t u) { return __uint_as_float(((unsigned)u) << 16); }
__device__ __forceinline__ ushort_t f2b(float f) {
  unsigned x = __float_as_uint(f);
  x += 0x7FFFu + ((x >> 16) & 1u);
  return (ushort_t)(x >> 16);
}
__device__ __forceinline__ unsigned pk2(float lo, float hi) {
  return (unsigned)f2b(lo) | ((unsigned)f2b(hi) << 16);
}
__device__ __forceinline__ float2 b2f2(unsigned u) {
  return make_float2(__uint_as_float(u << 16), __uint_as_float(u & 0xFFFF0000u));
}
__device__ __forceinline__ void atomicMaxFloat(float* addr, float val) {
  if (val >= 0.f) atomicMax((int*)addr, __float_as_int(val));
  else            atomicMin((unsigned int*)addr, __float_as_uint(val));
}

// ---------------- scalar prep
__global__ void prep_scalars(const float* __restrict__ theta, const float* __restrict__ rel_imp,
                             float* __restrict__ scal) {
  int t = threadIdx.x;
  if (t < 7) scal[t] = 1.f - sigf(theta[t]);
  if (t < 21) {
    const int partner[7] = {1, 0, 4, 5, 2, 3, -1};
    int l = t / 7, r = t % 7;
    float rw = sigf(rel_imp[t]);
    float w;
    if (partner[r] < 0) w = 1.f;
    else {
      float rwp = sigf(rel_imp[l * 7 + partner[r]]);
      float e0 = expf(rw), e1 = expf(rwp);
      w = e0 / (e0 + e1);
    }
    scal[8 + t] = w * rw;
  }
}

// ---------------- weight transpose + bf16 cast: Wt[mat][n][k] = f2b(W[mat][k][n])
__global__ __launch_bounds__(256) void transpose_weights(
    const float* __restrict__ Wq, const float* __restrict__ Wk, const float* __restrict__ Wv,
    const float* __restrict__ Wmsg, const float* __restrict__ Wo, const float* __restrict__ We1,
    ushort_t* __restrict__ Wt) {
  int mat = blockIdx.x;
  const float* src;
  if (mat < 21)      src = Wq   + (size_t)mat * 16384;
  else if (mat < 42) src = Wk   + (size_t)(mat - 21) * 16384;
  else if (mat < 63) src = Wv   + (size_t)(mat - 42) * 16384;
  else if (mat < 84) src = Wmsg + (size_t)(mat - 63) * 16384;
  else if (mat < 99) src = Wo   + (size_t)(mat - 84) * 16384;
  else               src = We1  + (size_t)(mat - 99) * 16384;
  __shared__ ushort_t lds[16384];
  int t = threadIdx.x;
  for (int i = 0; i < 64; i++) {
    int u = t + i * 256;            // u = k*128 + n
    int k = u >> 7;
    int byte = (u * 2) ^ ((k & 15) << 2);
    *(ushort_t*)((char*)lds + byte) = f2b(src[u]);
  }
  __syncthreads();
  ushort_t* dst = Wt + (size_t)mat * 16384;
  for (int i = 0; i < 64; i++) {
    int u = t + i * 256;            // u = n*128 + k
    int n = u >> 7, k = u & 127;
    int byte = ((k * 128 + n) * 2) ^ ((k & 15) << 2);
    dst[u] = *(ushort_t*)((char*)lds + byte);
  }
}

// ---------------- input projection: h = elu(x @ Win + b_in)  (bf16 out, 4 nodes/block)
__global__ __launch_bounds__(512) void in_proj(const float* __restrict__ x, const float* __restrict__ Win,
                                               const float* __restrict__ bin, ushort_t* __restrict__ Hout,
                                               int n, int F) {
  __shared__ float xs[4 * 24];
  int nl = threadIdx.x >> 7, c = threadIdx.x & 127;
  int node = blockIdx.x * 4 + nl;
  if (c < F && node < n) xs[nl * 24 + c] = x[(size_t)node * F + c];
  __syncthreads();
  if (node >= n) return;
  float acc = bin[c];
  for (int f = 0; f < F; f++) acc = fmaf(xs[nl * 24 + f], Win[f * 128 + c], acc);
  Hout[(size_t)node * 128 + c] = f2b(eluf(acc));
}

// ---------------- MFMA GEMM: C[n,BN] = A[n,128] @ Wt^T  (Wt in [n_col][k] bf16 layout)
// MODE 0: A bf16 -> C bf16 (SPLIT: cols<128 -> C1, else C2, both stride 128; else C1 stride BN)
// MODE 1: A f32 (S, z-normalized) -> comb bf16 += coef*(acc + deg*bmsg)
// MODE 4: same as 1 but init (=)
// MODE 2: A bf16 (comb) -> y = acc + b2f(C1) + bo; LN; elu; C1 = bf16 (in-place h), BN=128
template<int MODE, int BN, bool SPLIT>
__global__ __launch_bounds__(256) void gemm_mfma(
    const void* __restrict__ Ap, const ushort_t* __restrict__ Bt, const ushort_t* __restrict__ Bt2,
    ushort_t* __restrict__ C1, ushort_t* __restrict__ C2, int n,
    const float* __restrict__ coefp, const float* __restrict__ deg, const float* __restrict__ zb,
    const float* __restrict__ bvec, const float* __restrict__ lng, const float* __restrict__ lnb) {
  __shared__ char sm[16384 + BN * 256];
  ushort_t* As = (ushort_t*)sm;
  char* Bs = sm + 16384;
  int tid = threadIdx.x;
  int base = blockIdx.x * 64;

  // ---- stage B (Wt, [BN][128] bf16, 16B units, XOR swizzle) ----
#pragma unroll
  for (int i = 0; i < BN / 16; i++) {
    int u = tid + i * 256;
    int nrow = u >> 4;
    const ushort_t* sp = (BN == 256 && u >= 2048) ? (Bt2 + (size_t)(u - 2048) * 8)
                                                  : (Bt + (size_t)u * 8);
    uint4 w = *(const uint4*)sp;
    int byte = (u * 16) ^ ((nrow & 7) << 4);
    *(uint4*)(Bs + byte) = w;
  }
  // ---- stage A ([64][128] bf16) ----
  if (MODE == 1 || MODE == 4) {
    const float* Af = (const float*)Ap;
#pragma unroll
    for (int i = 0; i < 4; i++) {
      int u = tid + i * 256;
      int row = u >> 4, c8 = u & 15;
      int grow = base + row;
      uint4 o = make_uint4(0, 0, 0, 0);
      if (grow < n) {
        const float4 f0 = *(const float4*)&Af[(size_t)grow * 128 + c8 * 8];
        const float4 f1 = *(const float4*)&Af[(size_t)grow * 128 + c8 * 8 + 4];
        float inv = 1.f / (zb[grow * 4 + (c8 >> 2)] + 1e-10f);
        o.x = pk2(f0.x * inv, f0.y * inv);
        o.y = pk2(f0.z * inv, f0.w * inv);
        o.z = pk2(f1.x * inv, f1.y * inv);
        o.w = pk2(f1.z * inv, f1.w * inv);
      }
      int byte = (u * 16) ^ ((row & 7) << 4);
      *(uint4*)((char*)As + byte) = o;
    }
  } else {
    const ushort_t* Ab = (const ushort_t*)Ap;
#pragma unroll
    for (int i = 0; i < 4; i++) {
      int u = tid + i * 256;
      int row = u >> 4, c16 = u & 15;
      int grow = base + row;
      uint4 v = make_uint4(0, 0, 0, 0);
      if (grow < n) v = *(const uint4*)&Ab[(size_t)grow * 128 + c16 * 8];
      int byte = (u * 16) ^ ((row & 7) << 4);
      *(uint4*)((char*)As + byte) = v;
    }
  }
  __syncthreads();

  // ---- MFMA compute ----
  constexpr int NF = BN / 64;
  int lane = tid & 63, wv = tid >> 6;
  int i16 = lane & 15, seg = lane >> 4;
  int wcol = wv * (BN / 4);
  f32x4 acc[4][NF] = {};
#pragma unroll
  for (int s = 0; s < 4; s++) {
    bf16x8 a[4], b[NF];
#pragma unroll
    for (int m = 0; m < 4; m++) {
      int row = m * 16 + i16;
      int byte = (row * 256 + s * 64 + seg * 16) ^ ((row & 7) << 4);
      a[m] = *(const bf16x8*)((char*)As + byte);
    }
#pragma unroll
    for (int nn = 0; nn < NF; nn++) {
      int nr = wcol + nn * 16 + i16;
      int byte = (nr * 256 + s * 64 + seg * 16) ^ ((nr & 7) << 4);
      b[nn] = *(const bf16x8*)(Bs + byte);
    }
#pragma unroll
    for (int m = 0; m < 4; m++)
#pragma unroll
      for (int nn = 0; nn < NF; nn++)
        acc[m][nn] = __builtin_amdgcn_mfma_f32_16x16x32_bf16(a[m], b[nn], acc[m][nn], 0, 0, 0);
  }

  // ---- epilogue ----
  if (MODE == 0) {
#pragma unroll
    for (int m = 0; m < 4; m++) {
#pragma unroll
      for (int i = 0; i < 4; i++) {
        int grow = base + m * 16 + seg * 4 + i;
        if (grow >= n) continue;
#pragma unroll
        for (int nn = 0; nn < NF; nn++) {
          int col = wcol + nn * 16 + i16;
          ushort_t val = f2b(acc[m][nn][i]);
          if (SPLIT) {
            if (col < 128) C1[(size_t)grow * 128 + col] = val;
            else           C2[(size_t)grow * 128 + col - 128] = val;
          } else {
            C1[(size_t)grow * BN + col] = val;
          }
        }
      }
    }
  } else if (MODE == 1 || MODE == 4) {
    float coef = *coefp;
#pragma unroll
    for (int m = 0; m < 4; m++) {
#pragma unroll
      for (int i = 0; i < 4; i++) {
        int grow = base + m * 16 + seg * 4 + i;
        if (grow >= n) continue;
        float dg = deg[grow];
#pragma unroll
        for (int nn = 0; nn < NF; nn++) {
          int col = wcol + nn * 16 + i16;
          ushort_t* cp = &C1[(size_t)grow * 128 + col];
          float mv = coef * (acc[m][nn][i] + dg * bvec[col]);
          if (MODE == 1) mv += b2f(*cp);
          *cp = f2b(mv);
        }
      }
    }
  } else {  // MODE 2: fused residual + bias + LN + elu
    __syncthreads();                 // Bs reads done by all waves
    float* Ys = (float*)Bs;          // 64 x 128 f32 = 32 KB
#pragma unroll
    for (int m = 0; m < 4; m++) {
#pragma unroll
      for (int i = 0; i < 4; i++) {
        int rl = m * 16 + seg * 4 + i;
        int grow = base + rl;
        if (grow >= n) continue;
#pragma unroll
        for (int nn = 0; nn < NF; nn++) {
          int col = wcol + nn * 16 + i16;
          Ys[rl * 128 + col] = acc[m][nn][i] + b2f(C1[(size_t)grow * 128 + col]) + bvec[col];
        }
      }
    }
    __syncthreads();
    for (int rr = 0; rr < 16; rr++) {
      int rl = wv * 16 + rr;
      int grow = base + rl;
      if (grow >= n) continue;
      float y0 = Ys[rl * 128 + lane], y1 = Ys[rl * 128 + 64 + lane];
      float sum = y0 + y1;
#pragma unroll
      for (int mm = 32; mm; mm >>= 1) sum += __shfl_xor(sum, mm);
      float mu = sum * (1.f / 128.f);
      float d0 = y0 - mu, d1 = y1 - mu;
      float vs = d0 * d0 + d1 * d1;
#pragma unroll
      for (int mm = 32; mm; mm >>= 1) vs += __shfl_xor(vs, mm);
      float rs = rsqrtf(vs * (1.f / 128.f) + 1e-5f);
      C1[(size_t)grow * 128 + lane]      = f2b(eluf(d0 * rs * lng[lane] + lnb[lane]));
      C1[(size_t)grow * 128 + 64 + lane] = f2b(eluf(d1 * rs * lng[64 + lane] + lnb[64 + lane]));
    }
  }
}

// ---------------- per-relation clears
__global__ void clear_rel(float4* __restrict__ S4, float4* __restrict__ m4, float4* __restrict__ z4,
                          float* __restrict__ deg, int nd) {
  int idx = blockIdx.x * 256 + threadIdx.x;
  if (idx < nd * 32) S4[idx] = make_float4(0.f, 0.f, 0.f, 0.f);
  if (idx < nd) {
    m4[idx] = make_float4(-3.0e38f, -3.0e38f, -3.0e38f, -3.0e38f);
    z4[idx] = make_float4(0.f, 0.f, 0.f, 0.f);
    deg[idx] = 0.f;
  }
}

// ---------------- attention scores + segment max + degree
__global__ void score_max(const ushort_t* __restrict__ Q, const ushort_t* __restrict__ Kb,
                          const int* __restrict__ src, const int* __restrict__ dst,
                          const float* __restrict__ ew, const float* __restrict__ ews,
                          float* __restrict__ sbuf, float* __restrict__ m, float* __restrict__ deg) {
  int idx = blockIdx.x * 256 + threadIdx.x;
  if (idx >= EE * 4) return;
  int e = idx >> 2, hd = idx & 3;
  int s = src[e], d = dst[e];
  const uint4* qp = (const uint4*)&Q[(size_t)d * 128 + hd * 32];
  const uint4* kp = (const uint4*)&Kb[(size_t)s * 128 + hd * 32];
  float acc = 0.f;
#pragma unroll
  for (int i = 0; i < 4; i++) {
    uint4 qu = qp[i], ku = kp[i];
    float2 q0 = b2f2(qu.x), k0 = b2f2(ku.x);
    float2 q1 = b2f2(qu.y), k1 = b2f2(ku.y);
    float2 q2 = b2f2(qu.z), k2 = b2f2(ku.z);
    float2 q3 = b2f2(qu.w), k3 = b2f2(ku.w);
    acc += q0.x * k0.x + q0.y * k0.y + q1.x * k1.x + q1.y * k1.y
         + q2.x * k2.x + q2.y * k2.y + q3.x * k3.x + q3.y * k3.y;
  }
  float sc = acc * 0.17677669529663687f * ew[e] * (*ews);
  sbuf[idx] = sc;
  atomicMaxFloat(&m[d * 4 + hd], sc);
  if (hd == 0) atomicAdd(&deg[d], 1.f);
}

// ---------------- fused exp + z-sum + scatter ex*V into S
__global__ void scatter_fused(const int* __restrict__ src, const int* __restrict__ dst,
                              const ushort_t* __restrict__ V, const float* __restrict__ sbuf,
                              const float* __restrict__ m, float* __restrict__ z,
                              float* __restrict__ S) {
  int idx = blockIdx.x * 256 + threadIdx.x;
  if (idx >= EE * 16) return;
  int e = idx >> 4, c8 = idx & 15;
  int c = c8 * 8, hd = c >> 5;
  int s = src[e], d = dst[e];
  float ex = expf(sbuf[e * 4 + hd] - m[d * 4 + hd]);
  if ((c8 & 3) == 0) atomicAdd(&z[d * 4 + hd], ex);
  const uint4 v = *(const uint4*)&V[(size_t)s * 128 + c];
  float2 f0 = b2f2(v.x), f1 = b2f2(v.y), f2 = b2f2(v.z), f3 = b2f2(v.w);
  float* Sp = &S[(size_t)d * 128 + c];
  atomicAdd(Sp + 0, f0.x * ex); atomicAdd(Sp + 1, f0.y * ex);
  atomicAdd(Sp + 2, f1.x * ex); atomicAdd(Sp + 3, f1.y * ex);
  atomicAdd(Sp + 4, f2.x * ex); atomicAdd(Sp + 5, f2.y * ex);
  atomicAdd(Sp + 6, f3.x * ex); atomicAdd(Sp + 7, f3.y * ex);
}

__global__ void elu_bf16(ushort_t* __restrict__ x, int nelem) {
  int idx = blockIdx.x * 256 + threadIdx.x;
  if (idx >= nelem) return;
  x[idx] = f2b(eluf(b2f(x[idx])));
}

// ---------------- risk head
__global__ __launch_bounds__(256) void risk_head(const ushort_t* __restrict__ Hh,
                                                 const float* __restrict__ Wr1, const float* __restrict__ br1,
                                                 const float* __restrict__ Wr2, const float* __restrict__ br2,
                                                 float* __restrict__ out, int n) {
  int lane = threadIdx.x & 63;
  int node = blockIdx.x * 4 + (threadIdx.x >> 6);
  if (node >= n) return;
  const ushort_t* hp = &Hh[(size_t)node * 128];
  float acc = br1[lane];
  for (int k = 0; k < 128; k++) acc = fmaf(b2f(hp[k]), Wr1[k * 64 + lane], acc);
  float hid = eluf(acc);
  float v = hid * Wr2[lane];
#pragma unroll
  for (int mm = 32; mm; mm >>= 1) v += __shfl_xor(v, mm);
  if (lane == 0) out[node] = sigf(v + br2[0]);
}

// ---------------- edge head combine: out = sigmoid(elu(P1[src]+P2[dst]+be1) . We2 + be2)
__global__ __launch_bounds__(256) void edge_combine(const ushort_t* __restrict__ P1, const ushort_t* __restrict__ P2,
                                                    const int* __restrict__ src, const int* __restrict__ dst,
                                                    const float* __restrict__ be1, const float* __restrict__ We2,
                                                    const float* __restrict__ be2, float* __restrict__ out) {
  int lane = threadIdx.x & 63;
  int e = blockIdx.x * 4 + (threadIdx.x >> 6);
  if (e >= EE) return;
  int s = src[e], d = dst[e];
  const ushort_t* p1 = P1 + (size_t)s * 256;
  const ushort_t* p2 = P2 + (size_t)d * 256;
  float h0 = eluf(b2f(p1[lane])      + b2f(p2[lane])      + be1[lane]);
  float h1 = eluf(b2f(p1[64 + lane]) + b2f(p2[64 + lane]) + be1[64 + lane]);
  float v = h0 * We2[lane] + h1 * We2[64 + lane];
#pragma unroll
  for (int mm = 32; mm; mm >>= 1) v += __shfl_xor(v, mm);
  if (lane == 0) out[e] = sigf(v + be2[0]);
}

extern "C" void kernel_launch(void* const* d_in, const int* in_sizes, int n_in,
                              void* d_out, int out_size, void* d_ws, size_t ws_size,
                              hipStream_t stream) {
  (void)in_sizes; (void)n_in; (void)out_size;
  static const int NCNT_[5] = {60000, 20000, 40000, 40000, 10000};
  static const int FEAT_[5] = {22, 6, 14, 5, 9};
  static const int RSI[7] = {0, 1, 0, 0, 2, 4, 0};
  static const int RDI[7] = {1, 1, 2, 3, 2, 3, 0};
  static const int RFIRST[7] = {1, 0, 1, 1, 0, 0, 1};
  static const int ROFF[5] = {0, 60000, 80000, 120000, 160000};

  const float* x[5];    for (int i = 0; i < 5; i++) x[i] = (const float*)d_in[i];
  const int*   ei     = (const int*)d_in[5];
  const float* ew     = (const float*)d_in[6];
  const float* theta  = (const float*)d_in[7];
  const float* Win[5]; for (int i = 0; i < 5; i++) Win[i] = (const float*)d_in[8 + i];
  const float* b_in   = (const float*)d_in[13];
  const float* Wq     = (const float*)d_in[14];
  const float* Wk     = (const float*)d_in[15];
  const float* Wv     = (const float*)d_in[16];
  const float* Wmsg   = (const float*)d_in[17];
  const float* bmsg   = (const float*)d_in[18];
  const float* relimp = (const float*)d_in[19];
  const float* Wo     = (const float*)d_in[20];
  const float* bo     = (const float*)d_in[21];
  const float* lng    = (const float*)d_in[22];
  const float* lnb    = (const float*)d_in[23];
  const float* Wr1    = (const float*)d_in[24];
  const float* br1    = (const float*)d_in[25];
  const float* Wr2    = (const float*)d_in[26];
  const float* br2    = (const float*)d_in[27];
  const float* We1    = (const float*)d_in[28];
  const float* be1    = (const float*)d_in[29];
  const float* We2    = (const float*)d_in[30];
  const float* be2    = (const float*)d_in[31];
  float* out = (float*)d_out;

  // ---- workspace (~170 MB) ----
  char* ws = (char*)d_ws;
  size_t off = 0;
  auto alloc = [&](size_t bytes) -> void* {
    void* p = (void*)(ws + off);
    off = (off + bytes + 255) & ~(size_t)255;
    return p;
  };
  ushort_t* h    = (ushort_t*)alloc((size_t)TOTROWS * 128 * 2);
  ushort_t* comb = (ushort_t*)alloc((size_t)TOTROWS * 128 * 2);
  ushort_t* Qb   = (ushort_t*)alloc((size_t)60000 * 128 * 2);
  ushort_t* Kb   = (ushort_t*)alloc((size_t)60000 * 128 * 2);
  ushort_t* Vb   = (ushort_t*)alloc((size_t)60000 * 128 * 2);
  float* Sb   = (float*)alloc((size_t)60000 * 128 * 4);
  float* sbuf = (float*)alloc((size_t)EE * 4 * 4);
  float* mb   = (float*)alloc((size_t)60000 * 4 * 4);
  float* zb   = (float*)alloc((size_t)60000 * 4 * 4);
  float* degb = (float*)alloc((size_t)60000 * 4);
  ushort_t* Wt = (ushort_t*)alloc((size_t)101 * 16384 * 2);
  float* scal = (float*)alloc(256);
  if (off > ws_size) return;   // clean failure instead of fault if ws too small
  // Pcat (170000 x 256 bf16 = 87.04 MB) reuses comb+Qb+Kb+Vb (89.6 MB) after layers
  ushort_t* Pcat = comb;

  prep_scalars<<<1, 64, 0, stream>>>(theta, relimp, scal);
  transpose_weights<<<101, 256, 0, stream>>>(Wq, Wk, Wv, Wmsg, Wo, We1, Wt);

  for (int t = 0; t < 5; t++)
    in_proj<<<CDIV(NCNT_[t], 4), 512, 0, stream>>>(x[t], Win[t], b_in + t * 128,
                                                   h + (size_t)ROFF[t] * 128, NCNT_[t], FEAT_[t]);

  for (int l = 0; l < 3; l++) {
    for (int r = 0; r < 7; r++) {
      int si = RSI[r], di = RDI[r];
      int nds = NCNT_[si], ndd = NCNT_[di];
      ushort_t* hs = h + (size_t)ROFF[si] * 128;
      ushort_t* hd = h + (size_t)ROFF[di] * 128;
      const int* src = ei + (size_t)r * 2 * EE;
      const int* dst = src + EE;
      int lr = l * 7 + r;
      const ushort_t* WtQ = Wt + (size_t)lr * 16384;
      const ushort_t* WtK = Wt + (size_t)(21 + lr) * 16384;
      const ushort_t* WtV = Wt + (size_t)(42 + lr) * 16384;
      const ushort_t* WtM = Wt + (size_t)(63 + lr) * 16384;

      clear_rel<<<CDIV(ndd * 32, 256), 256, 0, stream>>>((float4*)Sb, (float4*)mb, (float4*)zb, degb, ndd);
      gemm_mfma<0, 128, false><<<CDIV(ndd, 64), 256, 0, stream>>>(
          hd, WtQ, nullptr, Qb, nullptr, ndd, nullptr, nullptr, nullptr, nullptr, nullptr, nullptr);
      gemm_mfma<0, 256, true><<<CDIV(nds, 64), 256, 0, stream>>>(
          hs, WtK, WtV, Kb, Vb, nds, nullptr, nullptr, nullptr, nullptr, nullptr, nullptr);
      score_max<<<CDIV(EE * 4, 256), 256, 0, stream>>>(Qb, Kb, src, dst, ew + (size_t)r * EE,
                                                       scal + r, sbuf, mb, degb);
      scatter_fused<<<CDIV(EE * 16, 256), 256, 0, stream>>>(src, dst, Vb, sbuf, mb, zb, Sb);
      ushort_t* cdst = comb + (size_t)ROFF[di] * 128;
      if (RFIRST[r])
        gemm_mfma<4, 128, false><<<CDIV(ndd, 64), 256, 0, stream>>>(
            Sb, WtM, nullptr, cdst, nullptr, ndd, scal + 8 + lr, degb, zb,
            bmsg + (size_t)lr * 128, nullptr, nullptr);
      else
        gemm_mfma<1, 128, false><<<CDIV(ndd, 64), 256, 0, stream>>>(
            Sb, WtM, nullptr, cdst, nullptr, ndd, scal + 8 + lr, degb, zb,
            bmsg + (size_t)lr * 128, nullptr, nullptr);
    }
    for (int i = 0; i < 4; i++) {
      ushort_t* hi = h + (size_t)ROFF[i] * 128;
      ushort_t* ci = comb + (size_t)ROFF[i] * 128;
      int li = l * 5 + i;
      gemm_mfma<2, 128, false><<<CDIV(NCNT_[i], 64), 256, 0, stream>>>(
          ci, Wt + (size_t)(84 + li) * 16384, nullptr, hi, nullptr, NCNT_[i],
          nullptr, nullptr, nullptr, bo + (size_t)li * 128, lng + (size_t)li * 128, lnb + (size_t)li * 128);
    }
    elu_bf16<<<CDIV(10000 * 128, 256), 256, 0, stream>>>(h + (size_t)ROFF[4] * 128, 10000 * 128);
  }

  // ---- heads ----
  // Pcat[node][0:128] = h @ We1a ; Pcat[node][128:256] = h @ We1b
  for (int t = 0; t < 5; t++)
    gemm_mfma<0, 256, false><<<CDIV(NCNT_[t], 64), 256, 0, stream>>>(
        h + (size_t)ROFF[t] * 128, Wt + (size_t)99 * 16384, Wt + (size_t)100 * 16384,
        Pcat + (size_t)ROFF[t] * 256, nullptr, NCNT_[t],
        nullptr, nullptr, nullptr, nullptr, nullptr, nullptr);

  risk_head<<<CDIV(TOTROWS, 4), 256, 0, stream>>>(h, Wr1, br1, Wr2, br2, out, TOTROWS);

  for (int r = 0; r < 7; r++) {
    int si = RSI[r], di = RDI[r];
    const int* src = ei + (size_t)r * 2 * EE;
    const int* dst = src + EE;
    edge_combine<<<CDIV(EE, 4), 256, 0, stream>>>(
        Pcat + (size_t)ROFF[si] * 256, Pcat + (size_t)ROFF[di] * 256 + 128,
        src, dst, be1, We2, be2, out + TOTROWS + (size_t)r * EE);
  }
}

// Round 5
// 4634.682 us; speedup vs baseline: 1.6115x; 1.1174x over previous
//
#include <hip/hip_runtime.h>

#define CDIV(a,b) (((a)+(b)-1)/(b))
#define EE 40000
#define TOTROWS 170000

typedef unsigned short ushort_t;
typedef short bf16x8 __attribute__((ext_vector_type(8)));
typedef float f32x4 __attribute__((ext_vector_type(4)));

__device__ __forceinline__ float eluf(float x) { return x > 0.f ? x : expm1f(x); }
__device__ __forceinline__ float sigf(float x) { return 1.f / (1.f + expf(-x)); }
__device__ __forceinline__ float b2f(ushort_t u) { return __uint_as_float(((unsigned)u) << 16); }
__device__ __forceinline__ ushort_t f2b(float f) {
  unsigned x = __float_as_uint(f);
  x += 0x7FFFu + ((x >> 16) & 1u);
  return (ushort_t)(x >> 16);
}
__device__ __forceinline__ unsigned pk2(float lo, float hi) {
  return (unsigned)f2b(lo) | ((unsigned)f2b(hi) << 16);
}
__device__ __forceinline__ float2 b2f2(unsigned u) {
  return make_float2(__uint_as_float(u << 16), __uint_as_float(u & 0xFFFF0000u));
}
__device__ __forceinline__ void atomicMaxFloat(float* addr, float val) {
  if (val >= 0.f) atomicMax((int*)addr, __float_as_int(val));
  else            atomicMin((unsigned int*)addr, __float_as_uint(val));
}

// ======== shared MFMA helpers (A: [64][128] bf16 swizzled; B: [BN][128] bf16 swizzled) ========
template<int BN>
__device__ __forceinline__ void stage_B(char* Bs, int tid, const ushort_t* Bt, const ushort_t* Bt2) {
#pragma unroll
  for (int i = 0; i < BN / 16; i++) {
    int u = tid + i * 256;
    int nrow = u >> 4;
    const ushort_t* sp = (BN == 256 && u >= 2048) ? (Bt2 + (size_t)(u - 2048) * 8)
                                                  : (Bt + (size_t)u * 8);
    uint4 w = *(const uint4*)sp;
    *(uint4*)(Bs + ((u * 16) ^ ((nrow & 7) << 4))) = w;
  }
}

__device__ __forceinline__ void stage_A_bf16(char* As, int tid, const ushort_t* Ab, int base, int n) {
#pragma unroll
  for (int i = 0; i < 4; i++) {
    int u = tid + i * 256;
    int row = u >> 4;
    int grow = base + row;
    uint4 v = make_uint4(0, 0, 0, 0);
    if (grow < n) v = *(const uint4*)&Ab[(size_t)grow * 128 + (u & 15) * 8];
    *(uint4*)(As + ((u * 16) ^ ((row & 7) << 4))) = v;
  }
}

template<int NF>
__device__ __forceinline__ void mfma_core(const char* As, const char* Bs, int lane, int wcol,
                                          f32x4 (&acc)[4][NF]) {
  int i16 = lane & 15, seg = lane >> 4;
#pragma unroll
  for (int s = 0; s < 4; s++) {
    bf16x8 a[4], b[NF];
#pragma unroll
    for (int m = 0; m < 4; m++) {
      int row = m * 16 + i16;
      a[m] = *(const bf16x8*)(As + ((row * 256 + s * 64 + seg * 16) ^ ((row & 7) << 4)));
    }
#pragma unroll
    for (int nn = 0; nn < NF; nn++) {
      int nr = wcol + nn * 16 + i16;
      b[nn] = *(const bf16x8*)(Bs + ((nr * 256 + s * 64 + seg * 16) ^ ((nr & 7) << 4)));
    }
#pragma unroll
    for (int m = 0; m < 4; m++)
#pragma unroll
      for (int nn = 0; nn < NF; nn++)
        acc[m][nn] = __builtin_amdgcn_mfma_f32_16x16x32_bf16(a[m], b[nn], acc[m][nn], 0, 0, 0);
  }
}

// ---------------- scalar prep
__global__ void prep_scalars(const float* __restrict__ theta, const float* __restrict__ rel_imp,
                             float* __restrict__ scal) {
  int t = threadIdx.x;
  if (t < 7) scal[t] = 1.f - sigf(theta[t]);
  if (t < 21) {
    const int partner[7] = {1, 0, 4, 5, 2, 3, -1};
    int l = t / 7, r = t % 7;
    float rw = sigf(rel_imp[t]);
    float w;
    if (partner[r] < 0) w = 1.f;
    else {
      float rwp = sigf(rel_imp[l * 7 + partner[r]]);
      float e0 = expf(rw), e1 = expf(rwp);
      w = e0 / (e0 + e1);
    }
    scal[8 + t] = w * rw;
  }
}

// ---------------- weight transpose + bf16 cast: Wt[mat][n][k] = f2b(W[mat][k][n])
__global__ __launch_bounds__(256) void transpose_weights(
    const float* __restrict__ Wq, const float* __restrict__ Wk, const float* __restrict__ Wv,
    const float* __restrict__ Wmsg, const float* __restrict__ Wo, const float* __restrict__ We1,
    ushort_t* __restrict__ Wt) {
  int mat = blockIdx.x;
  const float* src;
  if (mat < 21)      src = Wq   + (size_t)mat * 16384;
  else if (mat < 42) src = Wk   + (size_t)(mat - 21) * 16384;
  else if (mat < 63) src = Wv   + (size_t)(mat - 42) * 16384;
  else if (mat < 84) src = Wmsg + (size_t)(mat - 63) * 16384;
  else if (mat < 99) src = Wo   + (size_t)(mat - 84) * 16384;
  else               src = We1  + (size_t)(mat - 99) * 16384;
  __shared__ ushort_t lds[16384];
  int t = threadIdx.x;
  for (int i = 0; i < 64; i++) {
    int u = t + i * 256;            // u = k*128 + n
    int k = u >> 7;
    int byte = (u * 2) ^ ((k & 15) << 2);
    *(ushort_t*)((char*)lds + byte) = f2b(src[u]);
  }
  __syncthreads();
  ushort_t* dst = Wt + (size_t)mat * 16384;
  for (int i = 0; i < 64; i++) {
    int u = t + i * 256;            // u = n*128 + k
    int n = u >> 7, k = u & 127;
    int byte = ((k * 128 + n) * 2) ^ ((k & 15) << 2);
    dst[u] = *(ushort_t*)((char*)lds + byte);
  }
}

// ---------------- Wr1 transpose: Wt101[n*128+k] = f2b(Wr1[k*64+n]), n<64, k<128
__global__ void transpose_wr1(const float* __restrict__ Wr1, ushort_t* __restrict__ Wt101) {
  int u = blockIdx.x * 256 + threadIdx.x;   // grid 32 x 256 = 8192
  int n = u >> 7, k = u & 127;
  Wt101[u] = f2b(Wr1[k * 64 + n]);
}

// ---------------- batched input projection over all 170k nodes
__global__ __launch_bounds__(512) void in_proj_all(
    const float* __restrict__ x0, const float* __restrict__ x1, const float* __restrict__ x2,
    const float* __restrict__ x3, const float* __restrict__ x4,
    const float* __restrict__ W0, const float* __restrict__ W1, const float* __restrict__ W2,
    const float* __restrict__ W3, const float* __restrict__ W4,
    const float* __restrict__ b_in, ushort_t* __restrict__ Hout) {
  __shared__ float xs[4 * 24];
  int nl = threadIdx.x >> 7, c = threadIdx.x & 127;
  int node = blockIdx.x * 4 + nl;
  if (node >= TOTROWS) return;
  int t = (node >= 160000) ? 4 : (node >= 120000) ? 3 : (node >= 80000) ? 2 : (node >= 60000) ? 1 : 0;
  const int ROFF_[5] = {0, 60000, 80000, 120000, 160000};
  const int FEAT_[5] = {22, 6, 14, 5, 9};
  const float* xp = (t == 0) ? x0 : (t == 1) ? x1 : (t == 2) ? x2 : (t == 3) ? x3 : x4;
  const float* Wp = (t == 0) ? W0 : (t == 1) ? W1 : (t == 2) ? W2 : (t == 3) ? W3 : W4;
  int F = FEAT_[t];
  int ln = node - ROFF_[t];
  if (c < F) xs[nl * 24 + c] = xp[(size_t)ln * F + c];
  __syncthreads();
  float acc = b_in[t * 128 + c];
  for (int f = 0; f < F; f++) acc = fmaf(xs[nl * 24 + f], Wp[f * 128 + c], acc);
  Hout[(size_t)node * 128 + c] = f2b(eluf(acc));
}

// ---------------- fused QKV projections + per-relation state clear
// blocks [0, nqb): Q = hd @ WtQ^T (BN=128) + clear Sb/mb/zb/degb rows
// blocks [nqb, nqb+nkb): K|V = hs @ [WtK;WtV]^T (BN=256 split)
__global__ __launch_bounds__(256) void qkv_clear(
    const ushort_t* __restrict__ hd, const ushort_t* __restrict__ hs,
    const ushort_t* __restrict__ WtQ, const ushort_t* __restrict__ WtK, const ushort_t* __restrict__ WtV,
    ushort_t* __restrict__ Qb, ushort_t* __restrict__ Kb, ushort_t* __restrict__ Vb,
    int ndd, int nds,
    float* __restrict__ Sb, float* __restrict__ mb, float* __restrict__ zb, float* __restrict__ degb) {
  __shared__ char sm[16384 + 65536];
  char* As = sm;
  char* Bs = sm + 16384;
  int tid = threadIdx.x;
  int nqb = (ndd + 63) >> 6;
  int lane = tid & 63, wv = tid >> 6;

  if ((int)blockIdx.x < nqb) {
    int base = blockIdx.x * 64;
    // clear per-relation state for rows [base, base+64)
    {
      float4* Sb4 = (float4*)Sb;
#pragma unroll
      for (int i = 0; i < 8; i++) {
        int j = tid + i * 256;
        int row = base + (j >> 5);
        if (row < ndd) Sb4[(size_t)row * 32 + (j & 31)] = make_float4(0.f, 0.f, 0.f, 0.f);
      }
      int row = base + (tid >> 2);
      if (row < ndd) { mb[row * 4 + (tid & 3)] = -3.0e38f; zb[row * 4 + (tid & 3)] = 0.f; }
      if (tid < 64 && base + tid < ndd) degb[base + tid] = 0.f;
    }
    stage_B<128>(Bs, tid, WtQ, nullptr);
    stage_A_bf16(As, tid, hd, base, ndd);
    __syncthreads();
    f32x4 acc[4][2] = {};
    mfma_core<2>(As, Bs, lane, wv * 32, acc);
    int i16 = lane & 15, seg = lane >> 4;
#pragma unroll
    for (int m = 0; m < 4; m++)
#pragma unroll
      for (int i = 0; i < 4; i++) {
        int grow = base + m * 16 + seg * 4 + i;
        if (grow >= ndd) continue;
#pragma unroll
        for (int nn = 0; nn < 2; nn++) {
          int col = wv * 32 + nn * 16 + i16;
          Qb[(size_t)grow * 128 + col] = f2b(acc[m][nn][i]);
        }
      }
  } else {
    int base = (blockIdx.x - nqb) * 64;
    stage_B<256>(Bs, tid, WtK, WtV);
    stage_A_bf16(As, tid, hs, base, nds);
    __syncthreads();
    f32x4 acc[4][4] = {};
    mfma_core<4>(As, Bs, lane, wv * 64, acc);
    int i16 = lane & 15, seg = lane >> 4;
#pragma unroll
    for (int m = 0; m < 4; m++)
#pragma unroll
      for (int i = 0; i < 4; i++) {
        int grow = base + m * 16 + seg * 4 + i;
        if (grow >= nds) continue;
#pragma unroll
        for (int nn = 0; nn < 4; nn++) {
          int col = wv * 64 + nn * 16 + i16;
          ushort_t val = f2b(acc[m][nn][i]);
          if (col < 128) Kb[(size_t)grow * 128 + col] = val;
          else           Vb[(size_t)grow * 128 + col - 128] = val;
        }
      }
  }
}

// ---------------- MFMA GEMM (msg accumulate + Pcat)
// MODE 0: A bf16 -> C1 bf16 stride BN (Pcat, BN=256)
// MODE 1: A f32 (S, z-normalized at stage) -> comb bf16 += coef*(acc + deg*bmsg)
// MODE 4: same as 1 but init (=)
template<int MODE, int BN>
__global__ __launch_bounds__(256) void gemm_mfma(
    const void* __restrict__ Ap, const ushort_t* __restrict__ Bt, const ushort_t* __restrict__ Bt2,
    ushort_t* __restrict__ C1, int n,
    const float* __restrict__ coefp, const float* __restrict__ deg, const float* __restrict__ zb,
    const float* __restrict__ bvec) {
  __shared__ char sm[16384 + BN * 256];
  char* As = sm;
  char* Bs = sm + 16384;
  int tid = threadIdx.x;
  int base = blockIdx.x * 64;

  stage_B<BN>(Bs, tid, Bt, Bt2);
  if (MODE == 1 || MODE == 4) {
    const float* Af = (const float*)Ap;
#pragma unroll
    for (int i = 0; i < 4; i++) {
      int u = tid + i * 256;
      int row = u >> 4, c8 = u & 15;
      int grow = base + row;
      uint4 o = make_uint4(0, 0, 0, 0);
      if (grow < n) {
        const float4 f0 = *(const float4*)&Af[(size_t)grow * 128 + c8 * 8];
        const float4 f1 = *(const float4*)&Af[(size_t)grow * 128 + c8 * 8 + 4];
        float inv = 1.f / (zb[grow * 4 + (c8 >> 2)] + 1e-10f);
        o.x = pk2(f0.x * inv, f0.y * inv);
        o.y = pk2(f0.z * inv, f0.w * inv);
        o.z = pk2(f1.x * inv, f1.y * inv);
        o.w = pk2(f1.z * inv, f1.w * inv);
      }
      *(uint4*)(As + ((u * 16) ^ ((row & 7) << 4))) = o;
    }
  } else {
    stage_A_bf16(As, tid, (const ushort_t*)Ap, base, n);
  }
  __syncthreads();

  constexpr int NF = BN / 64;
  int lane = tid & 63, wv = tid >> 6;
  int i16 = lane & 15, seg = lane >> 4;
  int wcol = wv * (BN / 4);
  f32x4 acc[4][NF] = {};
  mfma_core<NF>(As, Bs, lane, wcol, acc);

  if (MODE == 0) {
#pragma unroll
    for (int m = 0; m < 4; m++)
#pragma unroll
      for (int i = 0; i < 4; i++) {
        int grow = base + m * 16 + seg * 4 + i;
        if (grow >= n) continue;
#pragma unroll
        for (int nn = 0; nn < NF; nn++) {
          int col = wcol + nn * 16 + i16;
          C1[(size_t)grow * BN + col] = f2b(acc[m][nn][i]);
        }
      }
  } else {
    float coef = *coefp;
#pragma unroll
    for (int m = 0; m < 4; m++)
#pragma unroll
      for (int i = 0; i < 4; i++) {
        int grow = base + m * 16 + seg * 4 + i;
        if (grow >= n) continue;
        float dg = deg[grow];
#pragma unroll
        for (int nn = 0; nn < NF; nn++) {
          int col = wcol + nn * 16 + i16;
          ushort_t* cp = &C1[(size_t)grow * 128 + col];
          float mv = coef * (acc[m][nn][i] + dg * bvec[col]);
          if (MODE == 1) mv += b2f(*cp);
          *cp = f2b(mv);
        }
      }
  }
}

// ---------------- attention scores + segment max + degree
__global__ void score_max(const ushort_t* __restrict__ Q, const ushort_t* __restrict__ Kb,
                          const int* __restrict__ src, const int* __restrict__ dst,
                          const float* __restrict__ ew, const float* __restrict__ ews,
                          float* __restrict__ sbuf, float* __restrict__ m, float* __restrict__ deg) {
  int idx = blockIdx.x * 256 + threadIdx.x;
  if (idx >= EE * 4) return;
  int e = idx >> 2, hd = idx & 3;
  int s = src[e], d = dst[e];
  const uint4* qp = (const uint4*)&Q[(size_t)d * 128 + hd * 32];
  const uint4* kp = (const uint4*)&Kb[(size_t)s * 128 + hd * 32];
  float acc = 0.f;
#pragma unroll
  for (int i = 0; i < 4; i++) {
    uint4 qu = qp[i], ku = kp[i];
    float2 q0 = b2f2(qu.x), k0 = b2f2(ku.x);
    float2 q1 = b2f2(qu.y), k1 = b2f2(ku.y);
    float2 q2 = b2f2(qu.z), k2 = b2f2(ku.z);
    float2 q3 = b2f2(qu.w), k3 = b2f2(ku.w);
    acc += q0.x * k0.x + q0.y * k0.y + q1.x * k1.x + q1.y * k1.y
         + q2.x * k2.x + q2.y * k2.y + q3.x * k3.x + q3.y * k3.y;
  }
  float sc = acc * 0.17677669529663687f * ew[e] * (*ews);
  sbuf[idx] = sc;
  atomicMaxFloat(&m[d * 4 + hd], sc);
  if (hd == 0) atomicAdd(&deg[d], 1.f);
}

// ---------------- fused exp + z-sum + scatter ex*V into S
__global__ void scatter_fused(const int* __restrict__ src, const int* __restrict__ dst,
                              const ushort_t* __restrict__ V, const float* __restrict__ sbuf,
                              const float* __restrict__ m, float* __restrict__ z,
                              float* __restrict__ S) {
  int idx = blockIdx.x * 256 + threadIdx.x;
  if (idx >= EE * 16) return;
  int e = idx >> 4, c8 = idx & 15;
  int c = c8 * 8, hd = c >> 5;
  int s = src[e], d = dst[e];
  float ex = expf(sbuf[e * 4 + hd] - m[d * 4 + hd]);
  if ((c8 & 3) == 0) atomicAdd(&z[d * 4 + hd], ex);
  const uint4 v = *(const uint4*)&V[(size_t)s * 128 + c];
  float2 f0 = b2f2(v.x), f1 = b2f2(v.y), f2 = b2f2(v.z), f3 = b2f2(v.w);
  float* Sp = &S[(size_t)d * 128 + c];
  atomicAdd(Sp + 0, f0.x * ex); atomicAdd(Sp + 1, f0.y * ex);
  atomicAdd(Sp + 2, f1.x * ex); atomicAdd(Sp + 3, f1.y * ex);
  atomicAdd(Sp + 4, f2.x * ex); atomicAdd(Sp + 5, f2.y * ex);
  atomicAdd(Sp + 6, f3.x * ex); atomicAdd(Sp + 7, f3.y * ex);
}

// ---------------- batched Wo GEMM + residual + LN + elu for types 0..3, + AIAgent elu tail
#define WO_NB0 938
#define WO_C1 938
#define WO_C2 1251
#define WO_C3 1876
#define WO_C4 2501
#define WO_TOTAL 2814
__global__ __launch_bounds__(256) void wo_ln_all(
    ushort_t* __restrict__ h, const ushort_t* __restrict__ comb, const ushort_t* __restrict__ Wt,
    const float* __restrict__ bo, const float* __restrict__ lng, const float* __restrict__ lnb, int l) {
  int bb = blockIdx.x;
  int tid = threadIdx.x;
  if (bb >= WO_C4) {
    // AIAgent: h = elu(h), rows 160000..170000
    int idx16 = (bb - WO_C4) * 256 + tid;
    if (idx16 >= 80000) return;
    ushort_t* p = h + (size_t)160000 * 128 + (size_t)idx16 * 16;
    uint4 v0 = *(uint4*)p, v1 = *(uint4*)(p + 8);
    unsigned* u0 = (unsigned*)&v0;
    unsigned* u1 = (unsigned*)&v1;
#pragma unroll
    for (int i = 0; i < 4; i++) {
      float2 a = b2f2(u0[i]); u0[i] = pk2(eluf(a.x), eluf(a.y));
      float2 b = b2f2(u1[i]); u1[i] = pk2(eluf(b.x), eluf(b.y));
    }
    *(uint4*)p = v0; *(uint4*)(p + 8) = v1;
    return;
  }
  int ti, lb;
  if (bb < WO_C1)      { ti = 0; lb = bb; }
  else if (bb < WO_C2) { ti = 1; lb = bb - WO_C1; }
  else if (bb < WO_C3) { ti = 2; lb = bb - WO_C2; }
  else                 { ti = 3; lb = bb - WO_C3; }
  const int ROFF_[4] = {0, 60000, 80000, 120000};
  const int NCNT4_[4] = {60000, 20000, 40000, 40000};
  int n = NCNT4_[ti];
  int base = lb * 64;
  int li = l * 5 + ti;
  const ushort_t* A = comb + (size_t)ROFF_[ti] * 128;
  ushort_t* C1 = h + (size_t)ROFF_[ti] * 128;
  const ushort_t* Bt = Wt + (size_t)(84 + li) * 16384;
  const float* bvec = bo + (size_t)li * 128;
  const float* g = lng + (size_t)li * 128;
  const float* b = lnb + (size_t)li * 128;

  __shared__ char sm[16384 + 32768];
  char* As = sm;
  char* Bs = sm + 16384;
  stage_B<128>(Bs, tid, Bt, nullptr);
  stage_A_bf16(As, tid, A, base, n);
  __syncthreads();
  int lane = tid & 63, wv = tid >> 6;
  int i16 = lane & 15, seg = lane >> 4;
  f32x4 acc[4][2] = {};
  mfma_core<2>(As, Bs, lane, wv * 32, acc);

  __syncthreads();
  float* Ys = (float*)Bs;   // 64 x 128 f32 = 32 KB
#pragma unroll
  for (int m = 0; m < 4; m++)
#pragma unroll
    for (int i = 0; i < 4; i++) {
      int rl = m * 16 + seg * 4 + i;
      int grow = base + rl;
      if (grow >= n) continue;
#pragma unroll
      for (int nn = 0; nn < 2; nn++) {
        int col = wv * 32 + nn * 16 + i16;
        Ys[rl * 128 + col] = acc[m][nn][i] + b2f(C1[(size_t)grow * 128 + col]) + bvec[col];
      }
    }
  __syncthreads();
  for (int rr = 0; rr < 16; rr++) {
    int rl = wv * 16 + rr;
    int grow = base + rl;
    if (grow >= n) continue;
    float y0 = Ys[rl * 128 + lane], y1 = Ys[rl * 128 + 64 + lane];
    float sum = y0 + y1;
#pragma unroll
    for (int mm = 32; mm; mm >>= 1) sum += __shfl_xor(sum, mm);
    float mu = sum * (1.f / 128.f);
    float d0 = y0 - mu, d1 = y1 - mu;
    float vs = d0 * d0 + d1 * d1;
#pragma unroll
    for (int mm = 32; mm; mm >>= 1) vs += __shfl_xor(vs, mm);
    float rs = rsqrtf(vs * (1.f / 128.f) + 1e-5f);
    C1[(size_t)grow * 128 + lane]      = f2b(eluf(d0 * rs * g[lane] + b[lane]));
    C1[(size_t)grow * 128 + 64 + lane] = f2b(eluf(d1 * rs * g[64 + lane] + b[64 + lane]));
  }
}

// ---------------- MFMA risk head: out = sigmoid(elu(h@Wr1+br1)@Wr2+br2)
__global__ __launch_bounds__(256) void risk_mfma(
    const ushort_t* __restrict__ Hh, const ushort_t* __restrict__ Wt101,
    const float* __restrict__ br1, const float* __restrict__ Wr2, const float* __restrict__ br2,
    float* __restrict__ out) {
  __shared__ char sm[16384 + 16384 + 64 * 68 * 4];
  char* As = sm;
  char* Bs = sm + 16384;
  float* Hs = (float*)(sm + 32768);
  int tid = threadIdx.x;
  int base = blockIdx.x * 64;
  // stage B: 64 n-rows x 128 k bf16 = 1024 16B units
#pragma unroll
  for (int i = 0; i < 4; i++) {
    int u = tid + i * 256;
    int nrow = u >> 4;
    uint4 w = *(const uint4*)(Wt101 + (size_t)u * 8);
    *(uint4*)(Bs + ((u * 16) ^ ((nrow & 7) << 4))) = w;
  }
  stage_A_bf16(As, tid, Hh, base, TOTROWS);
  __syncthreads();
  int lane = tid & 63, wv = tid >> 6;
  int i16 = lane & 15, seg = lane >> 4;
  f32x4 acc[4][1] = {};
  mfma_core<1>(As, Bs, lane, wv * 16, acc);
#pragma unroll
  for (int m = 0; m < 4; m++)
#pragma unroll
    for (int i = 0; i < 4; i++) {
      int rl = m * 16 + seg * 4 + i;
      int col = wv * 16 + i16;
      Hs[rl * 68 + col] = eluf(acc[m][0][i] + br1[col]);
    }
  __syncthreads();
  float wr2r = Wr2[lane];
  for (int rr = 0; rr < 16; rr++) {
    int rl = wv * 16 + rr;
    int grow = base + rl;
    float v = Hs[rl * 68 + lane] * wr2r;
#pragma unroll
    for (int mm = 32; mm; mm >>= 1) v += __shfl_xor(v, mm);
    if (lane == 0 && grow < TOTROWS) out[grow] = sigf(v + br2[0]);
  }
}

// ---------------- batched edge heads for all 7 relations
__global__ __launch_bounds__(256) void edge_combine_all(
    const ushort_t* __restrict__ Pcat, const int* __restrict__ ei,
    const float* __restrict__ be1, const float* __restrict__ We2,
    const float* __restrict__ be2, float* __restrict__ out) {
  const int RSI_[7] = {0, 1, 0, 0, 2, 4, 0};
  const int RDI_[7] = {1, 1, 2, 3, 2, 3, 0};
  const int ROFF_[5] = {0, 60000, 80000, 120000, 160000};
  int bb = blockIdx.x;
  int r = bb / 10000;
  int lane = threadIdx.x & 63;
  int e = (bb % 10000) * 4 + (threadIdx.x >> 6);
  const int* src = ei + (size_t)r * 2 * EE;
  const int* dst = src + EE;
  int s = src[e], d = dst[e];
  const ushort_t* p1 = Pcat + ((size_t)(ROFF_[RSI_[r]] + s)) * 256;
  const ushort_t* p2 = Pcat + ((size_t)(ROFF_[RDI_[r]] + d)) * 256 + 128;
  float h0 = eluf(b2f(p1[lane])      + b2f(p2[lane])      + be1[lane]);
  float h1 = eluf(b2f(p1[64 + lane]) + b2f(p2[64 + lane]) + be1[64 + lane]);
  float v = h0 * We2[lane] + h1 * We2[64 + lane];
#pragma unroll
  for (int mm = 32; mm; mm >>= 1) v += __shfl_xor(v, mm);
  if (lane == 0) out[TOTROWS + (size_t)r * EE + e] = sigf(v + be2[0]);
}

extern "C" void kernel_launch(void* const* d_in, const int* in_sizes, int n_in,
                              void* d_out, int out_size, void* d_ws, size_t ws_size,
                              hipStream_t stream) {
  (void)in_sizes; (void)n_in; (void)out_size;
  static const int NCNT_[5] = {60000, 20000, 40000, 40000, 10000};
  static const int RSI[7] = {0, 1, 0, 0, 2, 4, 0};
  static const int RDI[7] = {1, 1, 2, 3, 2, 3, 0};
  static const int RFIRST[7] = {1, 0, 1, 1, 0, 0, 1};
  static const int ROFF[5] = {0, 60000, 80000, 120000, 160000};

  const float* x[5];    for (int i = 0; i < 5; i++) x[i] = (const float*)d_in[i];
  const int*   ei     = (const int*)d_in[5];
  const float* ew     = (const float*)d_in[6];
  const float* theta  = (const float*)d_in[7];
  const float* Win[5]; for (int i = 0; i < 5; i++) Win[i] = (const float*)d_in[8 + i];
  const float* b_in   = (const float*)d_in[13];
  const float* Wq     = (const float*)d_in[14];
  const float* Wk     = (const float*)d_in[15];
  const float* Wv     = (const float*)d_in[16];
  const float* Wmsg   = (const float*)d_in[17];
  const float* bmsg   = (const float*)d_in[18];
  const float* relimp = (const float*)d_in[19];
  const float* Wo     = (const float*)d_in[20];
  const float* bo     = (const float*)d_in[21];
  const float* lng    = (const float*)d_in[22];
  const float* lnb    = (const float*)d_in[23];
  const float* Wr1    = (const float*)d_in[24];
  const float* br1    = (const float*)d_in[25];
  const float* Wr2    = (const float*)d_in[26];
  const float* br2    = (const float*)d_in[27];
  const float* We1    = (const float*)d_in[28];
  const float* be1    = (const float*)d_in[29];
  const float* We2    = (const float*)d_in[30];
  const float* be2    = (const float*)d_in[31];
  float* out = (float*)d_out;

  // ---- workspace (~170 MB) ----
  char* ws = (char*)d_ws;
  size_t off = 0;
  auto alloc = [&](size_t bytes) -> void* {
    void* p = (void*)(ws + off);
    off = (off + bytes + 255) & ~(size_t)255;
    return p;
  };
  ushort_t* h    = (ushort_t*)alloc((size_t)TOTROWS * 128 * 2);
  ushort_t* comb = (ushort_t*)alloc((size_t)TOTROWS * 128 * 2);
  ushort_t* Qb   = (ushort_t*)alloc((size_t)60000 * 128 * 2);
  ushort_t* Kb   = (ushort_t*)alloc((size_t)60000 * 128 * 2);
  ushort_t* Vb   = (ushort_t*)alloc((size_t)60000 * 128 * 2);
  float* Sb   = (float*)alloc((size_t)60000 * 128 * 4);
  float* sbuf = (float*)alloc((size_t)EE * 4 * 4);
  float* mb   = (float*)alloc((size_t)60000 * 4 * 4);
  float* zb   = (float*)alloc((size_t)60000 * 4 * 4);
  float* degb = (float*)alloc((size_t)60000 * 4);
  ushort_t* Wt = (ushort_t*)alloc((size_t)102 * 16384 * 2);
  float* scal = (float*)alloc(256);
  if (off > ws_size) return;   // clean failure instead of fault if ws too small
  // Pcat (170000 x 256 bf16 = 87.04 MB) reuses comb+Qb+Kb+Vb (89.6 MB) after layers
  ushort_t* Pcat = comb;

  prep_scalars<<<1, 64, 0, stream>>>(theta, relimp, scal);
  transpose_weights<<<101, 256, 0, stream>>>(Wq, Wk, Wv, Wmsg, Wo, We1, Wt);
  transpose_wr1<<<32, 256, 0, stream>>>(Wr1, Wt + (size_t)101 * 16384);

  in_proj_all<<<CDIV(TOTROWS, 4), 512, 0, stream>>>(
      x[0], x[1], x[2], x[3], x[4], Win[0], Win[1], Win[2], Win[3], Win[4], b_in, h);

  for (int l = 0; l < 3; l++) {
    for (int r = 0; r < 7; r++) {
      int si = RSI[r], di = RDI[r];
      int nds = NCNT_[si], ndd = NCNT_[di];
      ushort_t* hs = h + (size_t)ROFF[si] * 128;
      ushort_t* hd = h + (size_t)ROFF[di] * 128;
      const int* src = ei + (size_t)r * 2 * EE;
      const int* dst = src + EE;
      int lr = l * 7 + r;
      const ushort_t* WtQ = Wt + (size_t)lr * 16384;
      const ushort_t* WtK = Wt + (size_t)(21 + lr) * 16384;
      const ushort_t* WtV = Wt + (size_t)(42 + lr) * 16384;
      const ushort_t* WtM = Wt + (size_t)(63 + lr) * 16384;

      qkv_clear<<<CDIV(ndd, 64) + CDIV(nds, 64), 256, 0, stream>>>(
          hd, hs, WtQ, WtK, WtV, Qb, Kb, Vb, ndd, nds, Sb, mb, zb, degb);
      score_max<<<CDIV(EE * 4, 256), 256, 0, stream>>>(Qb, Kb, src, dst, ew + (size_t)r * EE,
                                                       scal + r, sbuf, mb, degb);
      scatter_fused<<<CDIV(EE * 16, 256), 256, 0, stream>>>(src, dst, Vb, sbuf, mb, zb, Sb);
      ushort_t* cdst = comb + (size_t)ROFF[di] * 128;
      if (RFIRST[r])
        gemm_mfma<4, 128><<<CDIV(ndd, 64), 256, 0, stream>>>(
            Sb, WtM, nullptr, cdst, ndd, scal + 8 + lr, degb, zb, bmsg + (size_t)lr * 128);
      else
        gemm_mfma<1, 128><<<CDIV(ndd, 64), 256, 0, stream>>>(
            Sb, WtM, nullptr, cdst, ndd, scal + 8 + lr, degb, zb, bmsg + (size_t)lr * 128);
    }
    wo_ln_all<<<WO_TOTAL, 256, 0, stream>>>(h, comb, Wt, bo, lng, lnb, l);
  }

  // ---- heads ----
  gemm_mfma<0, 256><<<CDIV(TOTROWS, 64), 256, 0, stream>>>(
      h, Wt + (size_t)99 * 16384, Wt + (size_t)100 * 16384, Pcat, TOTROWS,
      nullptr, nullptr, nullptr, nullptr);

  risk_mfma<<<CDIV(TOTROWS, 64), 256, 0, stream>>>(
      h, Wt + (size_t)101 * 16384, br1, Wr2, br2, out);

  edge_combine_all<<<7 * CDIV(EE, 4), 256, 0, stream>>>(Pcat, ei, be1, We2, be2, out);
}

// Round 6
// 1743.165 us; speedup vs baseline: 4.2846x; 2.6588x over previous
//
#include <hip/hip_runtime.h>

#define CDIV(a,b) (((a)+(b)-1)/(b))
#define EE 40000
#define TOTROWS 170000
#define NDOFF 60001
#define NCHK 59

typedef unsigned short ushort_t;
typedef short bf16x8 __attribute__((ext_vector_type(8)));
typedef float f32x4 __attribute__((ext_vector_type(4)));

__device__ __forceinline__ float eluf(float x) { return x > 0.f ? x : expm1f(x); }
__device__ __forceinline__ float sigf(float x) { return 1.f / (1.f + expf(-x)); }
__device__ __forceinline__ float b2f(ushort_t u) { return __uint_as_float(((unsigned)u) << 16); }
__device__ __forceinline__ ushort_t f2b(float f) {
  unsigned x = __float_as_uint(f);
  x += 0x7FFFu + ((x >> 16) & 1u);
  return (ushort_t)(x >> 16);
}
__device__ __forceinline__ unsigned pk2(float lo, float hi) {
  return (unsigned)f2b(lo) | ((unsigned)f2b(hi) << 16);
}
__device__ __forceinline__ float2 b2f2(unsigned u) {
  return make_float2(__uint_as_float(u << 16), __uint_as_float(u & 0xFFFF0000u));
}

__constant__ const int NDD_C[7] = {20000, 20000, 40000, 40000, 40000, 40000, 60000};

// ======== shared MFMA helpers ========
template<int BN>
__device__ __forceinline__ void stage_B(char* Bs, int tid, const ushort_t* Bt, const ushort_t* Bt2) {
#pragma unroll
  for (int i = 0; i < BN / 16; i++) {
    int u = tid + i * 256;
    int nrow = u >> 4;
    const ushort_t* sp = (BN == 256 && u >= 2048) ? (Bt2 + (size_t)(u - 2048) * 8)
                                                  : (Bt + (size_t)u * 8);
    uint4 w = *(const uint4*)sp;
    *(uint4*)(Bs + ((u * 16) ^ ((nrow & 7) << 4))) = w;
  }
}

__device__ __forceinline__ void stage_A_bf16(char* As, int tid, const ushort_t* Ab, int base, int n) {
#pragma unroll
  for (int i = 0; i < 4; i++) {
    int u = tid + i * 256;
    int row = u >> 4;
    int grow = base + row;
    uint4 v = make_uint4(0, 0, 0, 0);
    if (grow < n) v = *(const uint4*)&Ab[(size_t)grow * 128 + (u & 15) * 8];
    *(uint4*)(As + ((u * 16) ^ ((row & 7) << 4))) = v;
  }
}

template<int NF>
__device__ __forceinline__ void mfma_core(const char* As, const char* Bs, int lane, int wcol,
                                          f32x4 (&acc)[4][NF]) {
  int i16 = lane & 15, seg = lane >> 4;
#pragma unroll
  for (int s = 0; s < 4; s++) {
    bf16x8 a[4], b[NF];
#pragma unroll
    for (int m = 0; m < 4; m++) {
      int row = m * 16 + i16;
      a[m] = *(const bf16x8*)(As + ((row * 256 + s * 64 + seg * 16) ^ ((row & 7) << 4)));
    }
#pragma unroll
    for (int nn = 0; nn < NF; nn++) {
      int nr = wcol + nn * 16 + i16;
      b[nn] = *(const bf16x8*)(Bs + ((nr * 256 + s * 64 + seg * 16) ^ ((nr & 7) << 4)));
    }
#pragma unroll
    for (int m = 0; m < 4; m++)
#pragma unroll
      for (int nn = 0; nn < NF; nn++)
        acc[m][nn] = __builtin_amdgcn_mfma_f32_16x16x32_bf16(a[m], b[nn], acc[m][nn], 0, 0, 0);
  }
}

// ---------------- scalar prep
__global__ void prep_scalars(const float* __restrict__ theta, const float* __restrict__ rel_imp,
                             float* __restrict__ scal) {
  int t = threadIdx.x;
  if (t < 7) scal[t] = 1.f - sigf(theta[t]);
  if (t < 21) {
    const int partner[7] = {1, 0, 4, 5, 2, 3, -1};
    int l = t / 7, r = t % 7;
    float rw = sigf(rel_imp[t]);
    float w;
    if (partner[r] < 0) w = 1.f;
    else {
      float rwp = sigf(rel_imp[l * 7 + partner[r]]);
      float e0 = expf(rw), e1 = expf(rwp);
      w = e0 / (e0 + e1);
    }
    scal[8 + t] = w * rw;
  }
}

// ---------------- weight transpose + bf16 cast
__global__ __launch_bounds__(256) void transpose_weights(
    const float* __restrict__ Wq, const float* __restrict__ Wk, const float* __restrict__ Wv,
    const float* __restrict__ Wmsg, const float* __restrict__ Wo, const float* __restrict__ We1,
    ushort_t* __restrict__ Wt) {
  int mat = blockIdx.x;
  const float* src;
  if (mat < 21)      src = Wq   + (size_t)mat * 16384;
  else if (mat < 42) src = Wk   + (size_t)(mat - 21) * 16384;
  else if (mat < 63) src = Wv   + (size_t)(mat - 42) * 16384;
  else if (mat < 84) src = Wmsg + (size_t)(mat - 63) * 16384;
  else if (mat < 99) src = Wo   + (size_t)(mat - 84) * 16384;
  else               src = We1  + (size_t)(mat - 99) * 16384;
  __shared__ ushort_t lds[16384];
  int t = threadIdx.x;
  for (int i = 0; i < 64; i++) {
    int u = t + i * 256;            // u = k*128 + n
    int k = u >> 7;
    int byte = (u * 2) ^ ((k & 15) << 2);
    *(ushort_t*)((char*)lds + byte) = f2b(src[u]);
  }
  __syncthreads();
  ushort_t* dst = Wt + (size_t)mat * 16384;
  for (int i = 0; i < 64; i++) {
    int u = t + i * 256;            // u = n*128 + k
    int n = u >> 7, k = u & 127;
    int byte = ((k * 128 + n) * 2) ^ ((k & 15) << 2);
    dst[u] = *(ushort_t*)((char*)lds + byte);
  }
}

__global__ void transpose_wr1(const float* __restrict__ Wr1, ushort_t* __restrict__ Wt101) {
  int u = blockIdx.x * 256 + threadIdx.x;   // 8192
  int n = u >> 7, k = u & 127;
  Wt101[u] = f2b(Wr1[k * 64 + n]);
}

// ---------------- batched input projection
__global__ __launch_bounds__(512) void in_proj_all(
    const float* __restrict__ x0, const float* __restrict__ x1, const float* __restrict__ x2,
    const float* __restrict__ x3, const float* __restrict__ x4,
    const float* __restrict__ W0, const float* __restrict__ W1, const float* __restrict__ W2,
    const float* __restrict__ W3, const float* __restrict__ W4,
    const float* __restrict__ b_in, ushort_t* __restrict__ Hout) {
  __shared__ float xs[4 * 24];
  int nl = threadIdx.x >> 7, c = threadIdx.x & 127;
  int node = blockIdx.x * 4 + nl;
  if (node >= TOTROWS) return;
  int t = (node >= 160000) ? 4 : (node >= 120000) ? 3 : (node >= 80000) ? 2 : (node >= 60000) ? 1 : 0;
  const int ROFF_[5] = {0, 60000, 80000, 120000, 160000};
  const int FEAT_[5] = {22, 6, 14, 5, 9};
  const float* xp = (t == 0) ? x0 : (t == 1) ? x1 : (t == 2) ? x2 : (t == 3) ? x3 : x4;
  const float* Wp = (t == 0) ? W0 : (t == 1) ? W1 : (t == 2) ? W2 : (t == 3) ? W3 : W4;
  int F = FEAT_[t];
  int ln = node - ROFF_[t];
  if (c < F) xs[nl * 24 + c] = xp[(size_t)ln * F + c];
  __syncthreads();
  float acc = b_in[t * 128 + c];
  for (int f = 0; f < F; f++) acc = fmaf(xs[nl * 24 + f], Wp[f * 128 + c], acc);
  Hout[(size_t)node * 128 + c] = f2b(eluf(acc));
}

// ================= CSR build (per relation, by dst) =================
__global__ void csr_clear(int* __restrict__ counts) {
  int idx = blockIdx.x * 256 + threadIdx.x;
  if (idx < 7 * NDOFF) counts[idx] = 0;
}

__global__ void csr_hist(const int* __restrict__ ei, int* __restrict__ counts) {
  int idx = blockIdx.x * 256 + threadIdx.x;
  if (idx >= 7 * EE) return;
  int r = idx / EE, e = idx - r * EE;
  int d = ei[(size_t)r * 2 * EE + EE + e];
  atomicAdd(&counts[r * NDOFF + d], 1);
}

// per-1024-chunk sums
__global__ __launch_bounds__(256) void csr_chunk(const int* __restrict__ counts, int* __restrict__ chunkSums) {
  int bb = blockIdx.x;                 // 7*NCHK
  int r = bb / NCHK, c = bb - r * NCHK;
  int ndd = NDD_C[r];
  int t = threadIdx.x;
  int v = 0;
#pragma unroll
  for (int j = 0; j < 4; j++) {
    int idx = c * 1024 + t + j * 256;
    if (idx < ndd) v += counts[r * NDOFF + idx];
  }
#pragma unroll
  for (int mm = 32; mm; mm >>= 1) v += __shfl_xor(v, mm);
  __shared__ int ws_[4];
  if ((t & 63) == 0) ws_[t >> 6] = v;
  __syncthreads();
  if (t == 0) chunkSums[bb] = ws_[0] + ws_[1] + ws_[2] + ws_[3];
}

__global__ void csr_chunkscan(const int* __restrict__ chunkSums, int* __restrict__ chunkOffs) {
  int r = threadIdx.x;
  if (r >= 7) return;
  int run = 0;
  for (int c = 0; c < NCHK; c++) {
    chunkOffs[r * NCHK + c] = run;
    run += chunkSums[r * NCHK + c];
  }
}

__global__ __launch_bounds__(1024) void csr_scan_final(
    const int* __restrict__ counts, const int* __restrict__ chunkOffs,
    int* __restrict__ offs, int* __restrict__ cursor) {
  int bb = blockIdx.x;
  int r = bb / NCHK, c = bb - r * NCHK;
  int ndd = NDD_C[r];
  int t = threadIdx.x;
  int idx = c * 1024 + t;
  int v = (idx < ndd) ? counts[r * NDOFF + idx] : 0;
  __shared__ int sc[1024];
  sc[t] = v;
  __syncthreads();
  for (int s = 1; s < 1024; s <<= 1) {
    int add = (t >= s) ? sc[t - s] : 0;
    __syncthreads();
    sc[t] += add;
    __syncthreads();
  }
  if (idx < ndd) {
    int excl = chunkOffs[r * NCHK + c] + sc[t] - v;
    offs[r * NDOFF + idx] = excl;
    cursor[r * NDOFF + idx] = excl;
  }
  if (t == 0 && c == 0) offs[r * NDOFF + ndd] = EE;
}

__global__ void csr_scatter(const int* __restrict__ ei, int* __restrict__ cursor, int* __restrict__ eids) {
  int idx = blockIdx.x * 256 + threadIdx.x;
  if (idx >= 7 * EE) return;
  int r = idx / EE, e = idx - r * EE;
  int d = ei[(size_t)r * 2 * EE + EE + e];
  int slot = atomicAdd(&cursor[r * NDOFF + d], 1);
  eids[r * EE + slot] = e;
}

// ---------------- fused QKV projections
__global__ __launch_bounds__(256) void qkv_proj(
    const ushort_t* __restrict__ hd, const ushort_t* __restrict__ hs,
    const ushort_t* __restrict__ WtQ, const ushort_t* __restrict__ WtK, const ushort_t* __restrict__ WtV,
    ushort_t* __restrict__ Qb, ushort_t* __restrict__ Kb, ushort_t* __restrict__ Vb,
    int ndd, int nds) {
  __shared__ char sm[16384 + 65536];
  char* As = sm;
  char* Bs = sm + 16384;
  int tid = threadIdx.x;
  int nqb = (ndd + 63) >> 6;
  int lane = tid & 63, wv = tid >> 6;
  int i16 = lane & 15, seg = lane >> 4;

  if ((int)blockIdx.x < nqb) {
    int base = blockIdx.x * 64;
    stage_B<128>(Bs, tid, WtQ, nullptr);
    stage_A_bf16(As, tid, hd, base, ndd);
    __syncthreads();
    f32x4 acc[4][2] = {};
    mfma_core<2>(As, Bs, lane, wv * 32, acc);
#pragma unroll
    for (int m = 0; m < 4; m++)
#pragma unroll
      for (int i = 0; i < 4; i++) {
        int grow = base + m * 16 + seg * 4 + i;
        if (grow >= ndd) continue;
#pragma unroll
        for (int nn = 0; nn < 2; nn++) {
          int col = wv * 32 + nn * 16 + i16;
          Qb[(size_t)grow * 128 + col] = f2b(acc[m][nn][i]);
        }
      }
  } else {
    int base = (blockIdx.x - nqb) * 64;
    stage_B<256>(Bs, tid, WtK, WtV);
    stage_A_bf16(As, tid, hs, base, nds);
    __syncthreads();
    f32x4 acc[4][4] = {};
    mfma_core<4>(As, Bs, lane, wv * 64, acc);
#pragma unroll
    for (int m = 0; m < 4; m++)
#pragma unroll
      for (int i = 0; i < 4; i++) {
        int grow = base + m * 16 + seg * 4 + i;
        if (grow >= nds) continue;
#pragma unroll
        for (int nn = 0; nn < 4; nn++) {
          int col = wv * 64 + nn * 16 + i16;
          ushort_t val = f2b(acc[m][nn][i]);
          if (col < 128) Kb[(size_t)grow * 128 + col] = val;
          else           Vb[(size_t)grow * 128 + col - 128] = val;
        }
      }
  }
}

// ---------------- CSR attention: scores + exact segment softmax + aggregation, no atomics
// one wave per dst node; lane = column; heads are 32-lane groups
__global__ __launch_bounds__(256) void attn_agg(
    const ushort_t* __restrict__ Qb, const ushort_t* __restrict__ Kb, const ushort_t* __restrict__ Vb,
    const int* __restrict__ offs, const int* __restrict__ eids, const int* __restrict__ srcv,
    const float* __restrict__ ew, const float* __restrict__ ews,
    ushort_t* __restrict__ Sb, float* __restrict__ degb, int ndd) {
  int node = blockIdx.x * 4 + (threadIdx.x >> 6);
  if (node >= ndd) return;
  int lane = threadIdx.x & 63;
  int beg = offs[node], end = offs[node + 1];
  float escale = ews[0] * 0.17677669529663687f;
  float q0 = b2f(Qb[(size_t)node * 128 + lane]);
  float q1 = b2f(Qb[(size_t)node * 128 + 64 + lane]);
  float m0 = -3.0e38f, m1 = -3.0e38f, z0 = 0.f, z1 = 0.f, a0 = 0.f, a1 = 0.f;
  for (int p = beg; p < end; p++) {
    int e = eids[p];
    int s = srcv[e];
    float k0 = b2f(Kb[(size_t)s * 128 + lane]);
    float k1 = b2f(Kb[(size_t)s * 128 + 64 + lane]);
    float p0 = q0 * k0, p1 = q1 * k1;
#pragma unroll
    for (int mm = 16; mm; mm >>= 1) {
      p0 += __shfl_xor(p0, mm);
      p1 += __shfl_xor(p1, mm);
    }
    float wgt = ew[e] * escale;
    float s0 = p0 * wgt, s1 = p1 * wgt;
    float nm0 = fmaxf(m0, s0), nm1 = fmaxf(m1, s1);
    float r0 = expf(m0 - nm0), r1 = expf(m1 - nm1);
    float e0 = expf(s0 - nm0), e1 = expf(s1 - nm1);
    float v0 = b2f(Vb[(size_t)s * 128 + lane]);
    float v1 = b2f(Vb[(size_t)s * 128 + 64 + lane]);
    z0 = z0 * r0 + e0; a0 = a0 * r0 + e0 * v0; m0 = nm0;
    z1 = z1 * r1 + e1; a1 = a1 * r1 + e1 * v1; m1 = nm1;
  }
  Sb[(size_t)node * 128 + lane]      = f2b(a0 / (z0 + 1e-10f));
  Sb[(size_t)node * 128 + 64 + lane] = f2b(a1 / (z1 + 1e-10f));
  if (lane == 0) degb[node] = (float)(end - beg);
}

// ---------------- MFMA GEMM (msg accumulate + Pcat); A always bf16
// MODE 0: C1 bf16 = acc, stride BN (Pcat, BN=256)
// MODE 1: comb bf16 += coef*(acc + deg*bmsg)
// MODE 4: comb bf16  = coef*(acc + deg*bmsg)
template<int MODE, int BN>
__global__ __launch_bounds__(256) void gemm_mfma(
    const ushort_t* __restrict__ Ap, const ushort_t* __restrict__ Bt, const ushort_t* __restrict__ Bt2,
    ushort_t* __restrict__ C1, int n,
    const float* __restrict__ coefp, const float* __restrict__ deg, const float* __restrict__ bvec) {
  __shared__ char sm[16384 + BN * 256];
  char* As = sm;
  char* Bs = sm + 16384;
  int tid = threadIdx.x;
  int base = blockIdx.x * 64;

  stage_B<BN>(Bs, tid, Bt, Bt2);
  stage_A_bf16(As, tid, Ap, base, n);
  __syncthreads();

  constexpr int NF = BN / 64;
  int lane = tid & 63, wv = tid >> 6;
  int i16 = lane & 15, seg = lane >> 4;
  int wcol = wv * (BN / 4);
  f32x4 acc[4][NF] = {};
  mfma_core<NF>(As, Bs, lane, wcol, acc);

  if (MODE == 0) {
#pragma unroll
    for (int m = 0; m < 4; m++)
#pragma unroll
      for (int i = 0; i < 4; i++) {
        int grow = base + m * 16 + seg * 4 + i;
        if (grow >= n) continue;
#pragma unroll
        for (int nn = 0; nn < NF; nn++) {
          int col = wcol + nn * 16 + i16;
          C1[(size_t)grow * BN + col] = f2b(acc[m][nn][i]);
        }
      }
  } else {
    float coef = *coefp;
#pragma unroll
    for (int m = 0; m < 4; m++)
#pragma unroll
      for (int i = 0; i < 4; i++) {
        int grow = base + m * 16 + seg * 4 + i;
        if (grow >= n) continue;
        float dg = deg[grow];
#pragma unroll
        for (int nn = 0; nn < NF; nn++) {
          int col = wcol + nn * 16 + i16;
          ushort_t* cp = &C1[(size_t)grow * 128 + col];
          float mv = coef * (acc[m][nn][i] + dg * bvec[col]);
          if (MODE == 1) mv += b2f(*cp);
          *cp = f2b(mv);
        }
      }
  }
}

// ---------------- batched Wo GEMM + residual + LN + elu, + AIAgent elu tail
#define WO_C1 938
#define WO_C2 1251
#define WO_C3 1876
#define WO_C4 2501
#define WO_TOTAL 2814
__global__ __launch_bounds__(256) void wo_ln_all(
    ushort_t* __restrict__ h, const ushort_t* __restrict__ comb, const ushort_t* __restrict__ Wt,
    const float* __restrict__ bo, const float* __restrict__ lng, const float* __restrict__ lnb, int l) {
  int bb = blockIdx.x;
  int tid = threadIdx.x;
  if (bb >= WO_C4) {
    int idx16 = (bb - WO_C4) * 256 + tid;
    if (idx16 >= 80000) return;
    ushort_t* p = h + (size_t)160000 * 128 + (size_t)idx16 * 16;
    uint4 v0 = *(uint4*)p, v1 = *(uint4*)(p + 8);
    unsigned* u0 = (unsigned*)&v0;
    unsigned* u1 = (unsigned*)&v1;
#pragma unroll
    for (int i = 0; i < 4; i++) {
      float2 a = b2f2(u0[i]); u0[i] = pk2(eluf(a.x), eluf(a.y));
      float2 b = b2f2(u1[i]); u1[i] = pk2(eluf(b.x), eluf(b.y));
    }
    *(uint4*)p = v0; *(uint4*)(p + 8) = v1;
    return;
  }
  int ti, lb;
  if (bb < WO_C1)      { ti = 0; lb = bb; }
  else if (bb < WO_C2) { ti = 1; lb = bb - WO_C1; }
  else if (bb < WO_C3) { ti = 2; lb = bb - WO_C2; }
  else                 { ti = 3; lb = bb - WO_C3; }
  const int ROFF_[4] = {0, 60000, 80000, 120000};
  const int NCNT4_[4] = {60000, 20000, 40000, 40000};
  int n = NCNT4_[ti];
  int base = lb * 64;
  int li = l * 5 + ti;
  const ushort_t* A = comb + (size_t)ROFF_[ti] * 128;
  ushort_t* C1 = h + (size_t)ROFF_[ti] * 128;
  const ushort_t* Bt = Wt + (size_t)(84 + li) * 16384;
  const float* bvec = bo + (size_t)li * 128;
  const float* g = lng + (size_t)li * 128;
  const float* b = lnb + (size_t)li * 128;

  __shared__ char sm[16384 + 32768];
  char* As = sm;
  char* Bs = sm + 16384;
  stage_B<128>(Bs, tid, Bt, nullptr);
  stage_A_bf16(As, tid, A, base, n);
  __syncthreads();
  int lane = tid & 63, wv = tid >> 6;
  int i16 = lane & 15, seg = lane >> 4;
  f32x4 acc[4][2] = {};
  mfma_core<2>(As, Bs, lane, wv * 32, acc);

  __syncthreads();
  float* Ys = (float*)Bs;
#pragma unroll
  for (int m = 0; m < 4; m++)
#pragma unroll
    for (int i = 0; i < 4; i++) {
      int rl = m * 16 + seg * 4 + i;
      int grow = base + rl;
      if (grow >= n) continue;
#pragma unroll
      for (int nn = 0; nn < 2; nn++) {
        int col = wv * 32 + nn * 16 + i16;
        Ys[rl * 128 + col] = acc[m][nn][i] + b2f(C1[(size_t)grow * 128 + col]) + bvec[col];
      }
    }
  __syncthreads();
  for (int rr = 0; rr < 16; rr++) {
    int rl = wv * 16 + rr;
    int grow = base + rl;
    if (grow >= n) continue;
    float y0 = Ys[rl * 128 + lane], y1 = Ys[rl * 128 + 64 + lane];
    float sum = y0 + y1;
#pragma unroll
    for (int mm = 32; mm; mm >>= 1) sum += __shfl_xor(sum, mm);
    float mu = sum * (1.f / 128.f);
    float d0 = y0 - mu, d1 = y1 - mu;
    float vs = d0 * d0 + d1 * d1;
#pragma unroll
    for (int mm = 32; mm; mm >>= 1) vs += __shfl_xor(vs, mm);
    float rs = rsqrtf(vs * (1.f / 128.f) + 1e-5f);
    C1[(size_t)grow * 128 + lane]      = f2b(eluf(d0 * rs * g[lane] + b[lane]));
    C1[(size_t)grow * 128 + 64 + lane] = f2b(eluf(d1 * rs * g[64 + lane] + b[64 + lane]));
  }
}

// ---------------- MFMA risk head
__global__ __launch_bounds__(256) void risk_mfma(
    const ushort_t* __restrict__ Hh, const ushort_t* __restrict__ Wt101,
    const float* __restrict__ br1, const float* __restrict__ Wr2, const float* __restrict__ br2,
    float* __restrict__ out) {
  __shared__ char sm[16384 + 16384 + 64 * 68 * 4];
  char* As = sm;
  char* Bs = sm + 16384;
  float* Hs = (float*)(sm + 32768);
  int tid = threadIdx.x;
  int base = blockIdx.x * 64;
#pragma unroll
  for (int i = 0; i < 4; i++) {
    int u = tid + i * 256;
    int nrow = u >> 4;
    uint4 w = *(const uint4*)(Wt101 + (size_t)u * 8);
    *(uint4*)(Bs + ((u * 16) ^ ((nrow & 7) << 4))) = w;
  }
  stage_A_bf16(As, tid, Hh, base, TOTROWS);
  __syncthreads();
  int lane = tid & 63, wv = tid >> 6;
  int i16 = lane & 15, seg = lane >> 4;
  f32x4 acc[4][1] = {};
  mfma_core<1>(As, Bs, lane, wv * 16, acc);
#pragma unroll
  for (int m = 0; m < 4; m++)
#pragma unroll
    for (int i = 0; i < 4; i++) {
      int rl = m * 16 + seg * 4 + i;
      int col = wv * 16 + i16;
      Hs[rl * 68 + col] = eluf(acc[m][0][i] + br1[col]);
    }
  __syncthreads();
  float wr2r = Wr2[lane];
  for (int rr = 0; rr < 16; rr++) {
    int rl = wv * 16 + rr;
    int grow = base + rl;
    float v = Hs[rl * 68 + lane] * wr2r;
#pragma unroll
    for (int mm = 32; mm; mm >>= 1) v += __shfl_xor(v, mm);
    if (lane == 0 && grow < TOTROWS) out[grow] = sigf(v + br2[0]);
  }
}

// ---------------- batched edge heads
__global__ __launch_bounds__(256) void edge_combine_all(
    const ushort_t* __restrict__ Pcat, const int* __restrict__ ei,
    const float* __restrict__ be1, const float* __restrict__ We2,
    const float* __restrict__ be2, float* __restrict__ out) {
  const int RSI_[7] = {0, 1, 0, 0, 2, 4, 0};
  const int RDI_[7] = {1, 1, 2, 3, 2, 3, 0};
  const int ROFF_[5] = {0, 60000, 80000, 120000, 160000};
  int bb = blockIdx.x;
  int r = bb / 10000;
  int lane = threadIdx.x & 63;
  int e = (bb % 10000) * 4 + (threadIdx.x >> 6);
  const int* src = ei + (size_t)r * 2 * EE;
  const int* dst = src + EE;
  int s = src[e], d = dst[e];
  const ushort_t* p1 = Pcat + ((size_t)(ROFF_[RSI_[r]] + s)) * 256;
  const ushort_t* p2 = Pcat + ((size_t)(ROFF_[RDI_[r]] + d)) * 256 + 128;
  float h0 = eluf(b2f(p1[lane])      + b2f(p2[lane])      + be1[lane]);
  float h1 = eluf(b2f(p1[64 + lane]) + b2f(p2[64 + lane]) + be1[64 + lane]);
  float v = h0 * We2[lane] + h1 * We2[64 + lane];
#pragma unroll
  for (int mm = 32; mm; mm >>= 1) v += __shfl_xor(v, mm);
  if (lane == 0) out[TOTROWS + (size_t)r * EE + e] = sigf(v + be2[0]);
}

extern "C" void kernel_launch(void* const* d_in, const int* in_sizes, int n_in,
                              void* d_out, int out_size, void* d_ws, size_t ws_size,
                              hipStream_t stream) {
  (void)in_sizes; (void)n_in; (void)out_size;
  static const int NCNT_[5] = {60000, 20000, 40000, 40000, 10000};
  static const int RSI[7] = {0, 1, 0, 0, 2, 4, 0};
  static const int RDI[7] = {1, 1, 2, 3, 2, 3, 0};
  static const int RFIRST[7] = {1, 0, 1, 1, 0, 0, 1};
  static const int ROFF[5] = {0, 60000, 80000, 120000, 160000};

  const float* x[5];    for (int i = 0; i < 5; i++) x[i] = (const float*)d_in[i];
  const int*   ei     = (const int*)d_in[5];
  const float* ew     = (const float*)d_in[6];
  const float* theta  = (const float*)d_in[7];
  const float* Win[5]; for (int i = 0; i < 5; i++) Win[i] = (const float*)d_in[8 + i];
  const float* b_in   = (const float*)d_in[13];
  const float* Wq     = (const float*)d_in[14];
  const float* Wk     = (const float*)d_in[15];
  const float* Wv     = (const float*)d_in[16];
  const float* Wmsg   = (const float*)d_in[17];
  const float* bmsg   = (const float*)d_in[18];
  const float* relimp = (const float*)d_in[19];
  const float* Wo     = (const float*)d_in[20];
  const float* bo     = (const float*)d_in[21];
  const float* lng    = (const float*)d_in[22];
  const float* lnb    = (const float*)d_in[23];
  const float* Wr1    = (const float*)d_in[24];
  const float* br1    = (const float*)d_in[25];
  const float* Wr2    = (const float*)d_in[26];
  const float* br2    = (const float*)d_in[27];
  const float* We1    = (const float*)d_in[28];
  const float* be1    = (const float*)d_in[29];
  const float* We2    = (const float*)d_in[30];
  const float* be2    = (const float*)d_in[31];
  float* out = (float*)d_out;

  // ---- workspace ----
  char* ws = (char*)d_ws;
  size_t off = 0;
  auto alloc = [&](size_t bytes) -> void* {
    void* p = (void*)(ws + off);
    off = (off + bytes + 255) & ~(size_t)255;
    return p;
  };
  ushort_t* h    = (ushort_t*)alloc((size_t)TOTROWS * 128 * 2);
  ushort_t* comb = (ushort_t*)alloc((size_t)TOTROWS * 128 * 2);
  ushort_t* Qb   = (ushort_t*)alloc((size_t)60000 * 128 * 2);
  ushort_t* Kb   = (ushort_t*)alloc((size_t)60000 * 128 * 2);
  ushort_t* Vb   = (ushort_t*)alloc((size_t)60000 * 128 * 2);
  ushort_t* Sb   = (ushort_t*)alloc((size_t)60000 * 128 * 2);   // normalized bf16 aggregate
  float* degb = (float*)alloc((size_t)60000 * 4);
  ushort_t* Wt = (ushort_t*)alloc((size_t)102 * 16384 * 2);
  int* counts  = (int*)alloc((size_t)7 * NDOFF * 4);
  int* cursor  = (int*)alloc((size_t)7 * NDOFF * 4);
  int* offsb   = (int*)alloc((size_t)7 * NDOFF * 4);
  int* eids    = (int*)alloc((size_t)7 * EE * 4);
  int* chunkS  = (int*)alloc((size_t)7 * NCHK * 4);
  int* chunkO  = (int*)alloc((size_t)7 * NCHK * 4);
  float* scal = (float*)alloc(256);
  if (off > ws_size) return;   // clean failure instead of fault if ws too small
  // Pcat (170000 x 256 bf16 = 87.04 MB) reuses comb+Qb+Kb+Vb (89.6 MB) after layers
  ushort_t* Pcat = comb;

  prep_scalars<<<1, 64, 0, stream>>>(theta, relimp, scal);
  transpose_weights<<<101, 256, 0, stream>>>(Wq, Wk, Wv, Wmsg, Wo, We1, Wt);
  transpose_wr1<<<32, 256, 0, stream>>>(Wr1, Wt + (size_t)101 * 16384);

  in_proj_all<<<CDIV(TOTROWS, 4), 512, 0, stream>>>(
      x[0], x[1], x[2], x[3], x[4], Win[0], Win[1], Win[2], Win[3], Win[4], b_in, h);

  // ---- CSR build (once; reused by all 3 layers) ----
  csr_clear<<<CDIV(7 * NDOFF, 256), 256, 0, stream>>>(counts);
  csr_hist<<<CDIV(7 * EE, 256), 256, 0, stream>>>(ei, counts);
  csr_chunk<<<7 * NCHK, 256, 0, stream>>>(counts, chunkS);
  csr_chunkscan<<<1, 64, 0, stream>>>(chunkS, chunkO);
  csr_scan_final<<<7 * NCHK, 1024, 0, stream>>>(counts, chunkO, offsb, cursor);
  csr_scatter<<<CDIV(7 * EE, 256), 256, 0, stream>>>(ei, cursor, eids);

  for (int l = 0; l < 3; l++) {
    for (int r = 0; r < 7; r++) {
      int si = RSI[r], di = RDI[r];
      int nds = NCNT_[si], ndd = NCNT_[di];
      ushort_t* hs = h + (size_t)ROFF[si] * 128;
      ushort_t* hd = h + (size_t)ROFF[di] * 128;
      const int* src = ei + (size_t)r * 2 * EE;
      int lr = l * 7 + r;
      const ushort_t* WtQ = Wt + (size_t)lr * 16384;
      const ushort_t* WtK = Wt + (size_t)(21 + lr) * 16384;
      const ushort_t* WtV = Wt + (size_t)(42 + lr) * 16384;
      const ushort_t* WtM = Wt + (size_t)(63 + lr) * 16384;

      qkv_proj<<<CDIV(ndd, 64) + CDIV(nds, 64), 256, 0, stream>>>(
          hd, hs, WtQ, WtK, WtV, Qb, Kb, Vb, ndd, nds);
      attn_agg<<<CDIV(ndd, 4), 256, 0, stream>>>(
          Qb, Kb, Vb, offsb + (size_t)r * NDOFF, eids + (size_t)r * EE, src,
          ew + (size_t)r * EE, scal + r, Sb, degb, ndd);
      ushort_t* cdst = comb + (size_t)ROFF[di] * 128;
      if (RFIRST[r])
        gemm_mfma<4, 128><<<CDIV(ndd, 64), 256, 0, stream>>>(
            Sb, WtM, nullptr, cdst, ndd, scal + 8 + lr, degb, bmsg + (size_t)lr * 128);
      else
        gemm_mfma<1, 128><<<CDIV(ndd, 64), 256, 0, stream>>>(
            Sb, WtM, nullptr, cdst, ndd, scal + 8 + lr, degb, bmsg + (size_t)lr * 128);
    }
    wo_ln_all<<<WO_TOTAL, 256, 0, stream>>>(h, comb, Wt, bo, lng, lnb, l);
  }

  // ---- heads ----
  gemm_mfma<0, 256><<<CDIV(TOTROWS, 64), 256, 0, stream>>>(
      h, Wt + (size_t)99 * 16384, Wt + (size_t)100 * 16384, Pcat, TOTROWS,
      nullptr, nullptr, nullptr);

  risk_mfma<<<CDIV(TOTROWS, 64), 256, 0, stream>>>(
      h, Wt + (size_t)101 * 16384, br1, Wr2, br2, out);

  edge_combine_all<<<7 * CDIV(EE, 4), 256, 0, stream>>>(Pcat, ei, be1, We2, be2, out);
}